// Round 8
// baseline (266.122 us; speedup 1.0000x reference)
//
#include <hip/hip_runtime.h>

#define LL 96
#define TT 24
#define HH 64
#define CC 8
#define GG 256   // 4*H
#define BT 8     // batches per block (decoder / fallback)
#define NB 512   // 4096/BT

typedef unsigned short u16t;
typedef unsigned int   u32t;
typedef __attribute__((ext_vector_type(8))) short bf16x8;
typedef __attribute__((ext_vector_type(4))) float f32x4;

__device__ __forceinline__ float b2f(u16t u){ union{u32t i; float f;} v; v.i=((u32t)u)<<16; return v.f; }
__device__ __forceinline__ u16t f2b(float f){ union{float f; u32t i;} v; v.f=f; u32t l=(v.i>>16)&1u; v.i+=0x7fffu+l; return (u16t)(v.i>>16); }
__device__ __forceinline__ float rcpf(float x){ return __builtin_amdgcn_rcpf(x); }
// fast sigmoid/tanh: v_exp + v_rcp (1-ulp), no precise-div chains
__device__ __forceinline__ float sigm(float x){ return rcpf(1.f + __expf(-x)); }
__device__ __forceinline__ float tanh2(float x){ return 1.f - 2.f*rcpf(__expf(2.f*x) + 1.f); }
__device__ __forceinline__ u32t pk2(float a, float b){ return (u32t)f2b(a) | ((u32t)f2b(b)<<16); }
__device__ __forceinline__ bf16x8 u2b8(uint4 u){ union{uint4 a; bf16x8 b;} v; v.a=u; return v.b; }
// A-layout slot (k, m): [kb][quad][m=16][x=8] shorts
__device__ __forceinline__ int aaddr(int k, int m){ return (((k>>5)*4 + ((k>>3)&3))*16 + m)*8 + (k&7); }

// LDS-only barrier: orders DS ops across the workgroup WITHOUT draining vmcnt.
__device__ __forceinline__ void bar_lds(){
    asm volatile("s_waitcnt lgkmcnt(0)" ::: "memory");
    __builtin_amdgcn_s_barrier();
    asm volatile("" ::: "memory");
    __builtin_amdgcn_sched_barrier(0);
}

// ---- dtype-agnostic load/store helpers --------------------------------------
template<bool F32> __device__ __forceinline__ float ldf(const void* p, size_t i){
    if constexpr (F32) return ((const float*)p)[i];
    else               return b2f(((const u16t*)p)[i]);
}
template<bool F32> __device__ __forceinline__ uint4 ld8p(const void* p, size_t i){
    if constexpr (F32){
        const float* f = (const float*)p + i;
        uint4 r; r.x = pk2(f[0],f[1]); r.y = pk2(f[2],f[3]);
                 r.z = pk2(f[4],f[5]); r.w = pk2(f[6],f[7]);
        return r;
    } else return *(const uint4*)((const u16t*)p + i);
}
template<bool F32> __device__ __forceinline__ void stf(void* p, size_t i, float v){
    if constexpr (F32) ((float*)p)[i] = v;
    else               ((u16t*)p)[i] = f2b(v);
}
template<bool F32> __device__ __forceinline__ float ldW_enc(const void* wih, const void* whh, int r, int k){
    if (k < CC)      return ldf<F32>(wih, (size_t)r*CC + k);
    else if (k < 72) return ldf<F32>(whh, (size_t)r*HH + (k-CC));
    else             return 0.f;
}

// dtype probe (bf16 confirmed live; kept as insurance — host dispatch via
// in_sizes normally launches only the matching template)
__device__ __forceinline__ bool inputs_are_f32(const void* bih){
    const u16t* p = (const u16t*)bih;
    int cnt = 0;
    #pragma unroll
    for (int i = 0; i < 64; ++i){
        u32t e = ((u32t)p[i] >> 7) & 0xFFu;
        cnt += (e >= 128u) ? 1 : 0;
    }
    return cnt > 0;
}

// =============================================================================
// Kernel 1 (R8): encoder BT=8, 512 blocks -> 2 blocks/CU (2 waves/SIMD).
// Occupancy ladder measured: enc4 (4 w/SIMD) 2330 cy/step issue-bound;
// enc16 (1 w/SIMD) 1825 cy/step latency-exposed (issue only ~590). This is
// the midpoint: fused-style 2-updates/lane mapping (all 64 lanes active, 60
// VALU-inst/wave incl. 10 quarter-rate transcendentals), 12 MFMA/wave, with
// 2-way TLP to hide ds/MFMA/trans latency. Per-SIMD issue ~900 cy/step.
// bar_lds keeps eoG stores + x prefetch in flight. Numerics bit-identical.
// =============================================================================
template<bool F32>
__global__ __launch_bounds__(256,2) void enc8_g(
    const void* __restrict__ x_enc,
    const void* __restrict__ eWih, const void* __restrict__ eWhh,
    const void* __restrict__ ebih, const void* __restrict__ ebhh,
    u16t* __restrict__ eoG, float* __restrict__ cG)
{
    if (inputs_are_f32(ebih) != F32) return;

    __shared__ __align__(16) short Abuf2[2][1536];

    const int tid = threadIdx.x;
    const int b0  = blockIdx.x * BT;
    const int col = tid & 15, quad = (tid >> 4) & 3, wv = tid >> 6;
    const int r0  = (quad >> 1) * 2;

    // encoder B-fragments + bias in registers
    bf16x8 Bf[4][3];
    float  biasg[4];
    #pragma unroll
    for (int g = 0; g < 4; ++g){
        int r = g*64 + wv*16 + col;
        biasg[g] = ldf<F32>(ebih, r) + ldf<F32>(ebhh, r);
        #pragma unroll
        for (int kb = 0; kb < 3; ++kb){
            bf16x8 v;
            #pragma unroll
            for (int x = 0; x < 8; ++x){
                int k = kb*32 + quad*8 + x;
                v[x] = (short)f2b(ldW_enc<F32>(eWih, eWhh, r, k));
            }
            Bf[g][kb] = v;
        }
    }
    for (int n = tid; n < 2*1536; n += 256) ((short*)Abuf2)[n] = 0;
    float sl = 0.f; size_t xbase = 0;
    if (tid < BT*CC){ int b = tid >> 3, i = tid & 7;
        xbase = (size_t)(b0+b)*(LL*CC) + i;
        sl = ldf<F32>(x_enc, xbase + (size_t)(LL-1)*CC);
    }
    __syncthreads();
    if (tid < BT*CC){ short v = (short)f2b(ldf<F32>(x_enc, xbase) - sl);
        Abuf2[0][tid] = v; Abuf2[0][tid + 64] = v; }   // x(0) + dup rows 8-15
    float xr = (tid < BT*CC) ? ldf<F32>(x_enc, xbase + CC) : 0.f;

    const int jmy = wv*16 + col;
    const int hwbase = aaddr(8 + jmy, 0);

    u32t ebase[2];
    #pragma unroll
    for (int rr = 0; rr < 2; ++rr){
        u32t bg = (u32t)(b0 + ((quad*4 + r0 + rr) & 7));
        ebase[rr] = (bg*4u + (u32t)(jmy>>4))*1536u + (u32t)((jmy&15)*8);
    }

    float creg[2] = {0.f,0.f};
    u32t  pkv[2]  = {0,0};

    #pragma unroll 2
    for (int t = 0; t < LL; ++t){
        bar_lds();
        const bf16x8* AbR = (const bf16x8*)Abuf2[t & 1];
        short*        AbW = Abuf2[(t + 1) & 1];
        bf16x8 a0 = AbR[(0*4 + quad)*16 + col];
        bf16x8 a1 = AbR[(1*4 + quad)*16 + col];
        bf16x8 a2 = AbR[(2*4 + quad)*16 + col];
        f32x4 acc[4];
        #pragma unroll
        for (int g = 0; g < 4; ++g){
            f32x4 a; a[0]=biasg[g]; a[1]=biasg[g]; a[2]=biasg[g]; a[3]=biasg[g];
            a = __builtin_amdgcn_mfma_f32_16x16x32_bf16(a0, Bf[g][0], a, 0,0,0);
            a = __builtin_amdgcn_mfma_f32_16x16x32_bf16(a1, Bf[g][1], a, 0,0,0);
            a = __builtin_amdgcn_mfma_f32_16x16x32_bf16(a2, Bf[g][2], a, 0,0,0);
            acc[g] = a;
        }
        int off = (t>>5)*512 + ((t>>3)&3)*128 + (t&7);
        // TWO elements per lane (all 64 lanes active): batch=(quad*4+r)&7, h=jmy
        #pragma unroll
        for (int rr = 0; rr < 2; ++rr){
            int r = r0 + rr;
            int b = (quad*4 + r) & 7;
            float c = sigm(acc[1][r])*creg[rr] + sigm(acc[0][r])*tanh2(acc[2][r]);
            float h = sigm(acc[3][r])*tanh2(c);
            creg[rr] = c;
            u16t hb = f2b(h);
            if ((t & 1) == 0) pkv[rr] = hb;
            else {
                pkv[rr] |= ((u32t)hb) << 16;
                *(u32t*)&eoG[ebase[rr] + (u32t)(off - 1)] = pkv[rr];
            }
            AbW[hwbase + b*8]     = (short)hb;
            AbW[hwbase + (b+8)*8] = (short)hb;
        }
        if (tid < BT*CC && t < LL-1){
            short v = (short)f2b(xr - sl);
            AbW[tid] = v; AbW[tid + 64] = v;
            int tn = (t+2 < LL) ? t+2 : LL-1;
            xr = ldf<F32>(x_enc, xbase + (size_t)tn*CC);
        }
    }
    #pragma unroll
    for (int rr = 0; rr < 2; ++rr)
        cG[(size_t)(b0 + ((quad*4 + r0 + rr) & 7))*HH + jmy] = creg[rr];
}

// =============================================================================
// Kernel 2: decoder, BT=8, 512 blocks. (R6 verbatim — parked: at its ~2000
// cy/phase structural floor; conflicts proven off critical path, register
// cliff blocks occupancy, grid=512 caps at 2 blocks/CU anyway.)
// =============================================================================
template<bool F32>
__global__ __launch_bounds__(256,2) void dec8_g(
    const void* __restrict__ x_enc,
    const void* __restrict__ embW, const void* __restrict__ embb,
    const void* __restrict__ attnW, const void* __restrict__ attnb,
    const void* __restrict__ combW, const void* __restrict__ combb,
    const void* __restrict__ dWih, const void* __restrict__ dWhh,
    const void* __restrict__ dbih, const void* __restrict__ dbhh,
    const void* __restrict__ outW, const void* __restrict__ outb,
    void* __restrict__ outp, const u16t* __restrict__ eoG,
    const float* __restrict__ cG)
{
    if (inputs_are_f32(dbih) != F32) return;

    __shared__ __align__(16) float slp[CC*10];
    __shared__ __align__(16) char  uni[17184];
    __shared__ __align__(16) u16t BaL[6*4*4*16*8];  // attnW frags: 24576B
    __shared__ __align__(16) u16t M1L[64*64];       // M1 = embW@outW, chunk-swizzled: 8192B
    __shared__ __align__(16) u16t oWL[8*64];        // outW, chunk-swizzled: 1024B

    const int tid = threadIdx.x;
    const int b0  = blockIdx.x * BT;
    const int col = tid & 15, quad = (tid >> 4) & 3, wv = tid >> 6;
    const int r0  = (quad >> 1) * 2;
    const int jmy = wv*16 + col;

    if (tid < BT*CC){ int b = tid >> 3, i = tid & 7;
        slp[i*10 + b] = ldf<F32>(x_enc, (size_t)(b0+b)*(LL*CC) + (size_t)(LL-1)*CC + i); }

    // ---------------- persistent register fragments (Bd, Bc) ----------------
    bf16x8 Bd[4][4];
    #pragma unroll
    for (int g = 0; g < 4; ++g){
        int r = g*64 + wv*16 + col;
        Bd[g][0] = u2b8(ld8p<F32>(dWih, (size_t)r*HH + quad*8));
        Bd[g][1] = u2b8(ld8p<F32>(dWih, (size_t)r*HH + 32 + quad*8));
        Bd[g][2] = u2b8(ld8p<F32>(dWhh, (size_t)r*HH + quad*8));
        Bd[g][3] = u2b8(ld8p<F32>(dWhh, (size_t)r*HH + 32 + quad*8));
    }
    bf16x8 Bc[4];
    #pragma unroll
    for (int kb = 0; kb < 4; ++kb)
        Bc[kb] = u2b8(ld8p<F32>(combW, (size_t)(wv*16+col)*128 + kb*32 + quad*8));
    bf16x8 zz = {0,0,0,0,0,0,0,0};

    // ---------------- LDS weight tables fill --------------------------------
    // attnW -> BaL, slot idx = lt*256 + kb*64 + quad*16 + col
    for (int idx = tid; idx < 1536; idx += 256){
        int lt_ = idx >> 8, kb_ = (idx >> 6) & 3, q_ = (idx >> 4) & 3, c_ = idx & 15;
        int row = lt_*16 + c_;
        u16t tmp[8];
        #pragma unroll
        for (int x = 0; x < 8; ++x)
            tmp[x] = f2b(ldf<F32>(attnW, (size_t)row*128 + kb_*32 + q_*8 + x));
        *(uint4*)&BaL[(size_t)idx*8] = *(uint4*)tmp;
    }
    // M1 = embW(64x8) @ outW(8x64), bf16, chunk-swizzled: elem (j,k) stored at
    // j*64 + ((k>>3 ^ (j&7))<<3 | (k&7))
    for (int idx = tid; idx < 1024; idx += 256){
        int j = idx >> 4, k0 = (idx & 15) * 4;
        float acc4[4] = {0.f,0.f,0.f,0.f};
        #pragma unroll
        for (int c = 0; c < 8; ++c){
            float e = ldf<F32>(embW, (size_t)j*CC + c);
            #pragma unroll
            for (int kk = 0; kk < 4; ++kk)
                acc4[kk] += e * ldf<F32>(outW, (size_t)c*HH + k0 + kk);
        }
        u16t tmp[4];
        #pragma unroll
        for (int kk = 0; kk < 4; ++kk) tmp[kk] = f2b(acc4[kk]);
        int sw = (((k0 >> 3) ^ (j & 7)) << 3) | (k0 & 7);
        *(uint2*)&M1L[j*64 + sw] = *(uint2*)tmp;
    }
    // outW -> oWL, same chunk swizzle (row c = 0..7)
    for (int n = tid; n < 512; n += 256){
        int c = n >> 6, k = n & 63;
        int sw = (((k >> 3) ^ (c & 7)) << 3) | (k & 7);
        oWL[c*64 + sw] = f2b(ldf<F32>(outW, n));
    }

    // ---------------- decoder LDS views + init ----------------
    float* decB  = (float*)(uni + 0);      // 256 f
    float* attnB = (float*)(uni + 1024);   // 96 f
    float* b1B   = (float*)(uni + 1408);   // 64 f : embb + embW@outb
    float* combB = (float*)(uni + 1664);   // 64 f
    float* outB  = (float*)(uni + 1920);   // 8 f
    float* Lg    = (float*)(uni + 1952);   // logits [l][9] stride-9 (3456B)
    u16t*  awB   = (u16t*)(uni + 5408);    // aw bf16 [b][96]
    u16t*  Ae    = (u16t*)(uni + 6944);    // emb A-buf
    u16t*  Ah0   = (u16t*)(uni + 8992);    // h A-buf ping
    u16t*  Ah1   = (u16t*)(uni + 11040);   // h A-buf pong
    u16t*  Actx  = (u16t*)(uni + 13088);   // ctx A-buf
    u16t*  Acmb  = (u16t*)(uni + 15136);   // comb A-buf

    float creg[2];
    #pragma unroll
    for (int rr = 0; rr < 2; ++rr){
        int b = (quad*4 + r0 + rr) & 7;
        // h(95) from eoG: off(95) = 2*512 + 3*128 + 7
        u16t hv = eoG[(((size_t)(b0+b)*4 + (size_t)(jmy>>4))*3 + 2)*512 + 3*128 + (jmy&15)*8 + 7];
        Ah0[aaddr(jmy, b)]   = hv;
        Ah0[aaddr(jmy, b+8)] = hv;
        creg[rr] = cG[(size_t)(b0+b)*HH + jmy];
    }
    decB[tid] = ldf<F32>(dbih, tid) + ldf<F32>(dbhh, tid);
    if (tid < LL) attnB[tid] = ldf<F32>(attnb, tid);
    if (tid < HH){
        float s = ldf<F32>(embb, tid);
        #pragma unroll
        for (int c = 0; c < 8; ++c)
            s += ldf<F32>(embW, (size_t)tid*CC + c) * ldf<F32>(outb, c);
        b1B[tid] = s;
    }
    if (tid < HH) combB[tid] = ldf<F32>(combb, tid);
    if (tid < CC) outB[tid]  = ldf<F32>(outb, tid);
    // Ae(0) = relu(embb) for all M rows (pred(-1) == 0 exactly)
    {
        float e0v = fmaxf(ldf<F32>(embb, jmy), 0.f);
        u16t ev = f2b(e0v);
        #pragma unroll
        for (int r = 0; r < 4; ++r)
            Ae[aaddr(jmy, quad*4 + r)] = ev;
    }
    __syncthreads();

    // eoG fragments for this wave's 2 batches -> registers
    const u16t* ebp = eoG + (size_t)(b0 + wv*2) * 6144;
    uint4 eF0[12], eF1[12];
    #pragma unroll
    for (int f = 0; f < 12; ++f) eF0[f] = *(const uint4*)(ebp + f*512 + quad*128 + col*8);
    #pragma unroll
    for (int f = 0; f < 12; ++f) eF1[f] = *(const uint4*)(ebp + 6144 + f*512 + quad*128 + col*8);

    const int lgS = tid & 31, bS = tid >> 5;
    const bf16x8* AeV   = (const bf16x8*)Ae;
    const bf16x8* ActxV = (const bf16x8*)Actx;
    const bf16x8* AcmbV = (const bf16x8*)Acmb;

    for (int t = 0; t < TT; ++t){
        u16t* AhR = (t & 1) ? Ah1 : Ah0;
        u16t* AhW = (t & 1) ? Ah0 : Ah1;
        const bf16x8* AhV = (const bf16x8*)AhR;

        // Phase A: attention logits via MFMA (Ba frags from LDS) -> Lg
        {
            bf16x8 ae0 = AeV[(0*4+quad)*16 + col], ae1 = AeV[(1*4+quad)*16 + col];
            bf16x8 ah0 = AhV[(0*4+quad)*16 + col], ah1 = AhV[(1*4+quad)*16 + col];
            const int ns = (wv < 2) ? 2 : 1;
            for (int s = 0; s < ns; ++s){
                int lt = (s == 0) ? wv : 4+wv;
                const u16t* bp = &BaL[lt*2048 + quad*128 + col*8];
                float bz = attnB[lt*16 + col];
                f32x4 a; a[0]=bz; a[1]=bz; a[2]=bz; a[3]=bz;
                a = __builtin_amdgcn_mfma_f32_16x16x32_bf16(ae0, *(const bf16x8*)&bp[0],    a, 0,0,0);
                a = __builtin_amdgcn_mfma_f32_16x16x32_bf16(ae1, *(const bf16x8*)&bp[512],  a, 0,0,0);
                a = __builtin_amdgcn_mfma_f32_16x16x32_bf16(ah0, *(const bf16x8*)&bp[1024], a, 0,0,0);
                a = __builtin_amdgcn_mfma_f32_16x16x32_bf16(ah1, *(const bf16x8*)&bp[1536], a, 0,0,0);
                if (quad < 2){
                    int rb = (lt*16+col)*9 + quad*4;
                    Lg[rb+0] = a[0]; Lg[rb+1] = a[1]; Lg[rb+2] = a[2]; Lg[rb+3] = a[3];
                }
            }
        }
        bar_lds();

        // Phase B: softmax (no max-subtract; logits bounded) + ctx MFMA
        {
            int l = lgS*3;
            float e0 = __expf(Lg[l*9 + bS]), e1 = __expf(Lg[(l+1)*9 + bS]), e2 = __expf(Lg[(l+2)*9 + bS]);
            float sm = e0 + e1 + e2;
            #pragma unroll
            for (int m = 16; m >= 1; m >>= 1) sm += __shfl_xor(sm, m, 32);
            float inv = rcpf(sm);
            awB[bS*96 + l]     = f2b(e0*inv);
            awB[bS*96 + l + 1] = f2b(e1*inv);
            awB[bS*96 + l + 2] = f2b(e2*inv);
        }
        // ctx via MFMA (A = aw broadcast, B = register eo frags); intra-wave RAW
        {
            const u16t* ap0 = awB + (wv*2)*96;
            bf16x8 f0 = *(const bf16x8*)(ap0 + quad*8);
            bf16x8 f1 = *(const bf16x8*)(ap0 + 32 + quad*8);
            bf16x8 f2 = *(const bf16x8*)(ap0 + 64 + quad*8);
            #pragma unroll
            for (int nt = 0; nt < 4; ++nt){
                f32x4 a; a[0]=0.f; a[1]=0.f; a[2]=0.f; a[3]=0.f;
                a = __builtin_amdgcn_mfma_f32_16x16x32_bf16(f0, u2b8(eF0[nt*3+0]), a, 0,0,0);
                a = __builtin_amdgcn_mfma_f32_16x16x32_bf16(f1, u2b8(eF0[nt*3+1]), a, 0,0,0);
                a = __builtin_amdgcn_mfma_f32_16x16x32_bf16(f2, u2b8(eF0[nt*3+2]), a, 0,0,0);
                if (quad == 0){
                    u16t v = f2b(a[0]);
                    Actx[aaddr(nt*16+col, wv*2)]   = v;
                    Actx[aaddr(nt*16+col, wv*2+8)] = v;
                }
            }
            const u16t* ap1 = awB + (wv*2+1)*96;
            bf16x8 g0 = *(const bf16x8*)(ap1 + quad*8);
            bf16x8 g1 = *(const bf16x8*)(ap1 + 32 + quad*8);
            bf16x8 g2 = *(const bf16x8*)(ap1 + 64 + quad*8);
            #pragma unroll
            for (int nt = 0; nt < 4; ++nt){
                f32x4 a; a[0]=0.f; a[1]=0.f; a[2]=0.f; a[3]=0.f;
                a = __builtin_amdgcn_mfma_f32_16x16x32_bf16(g0, u2b8(eF1[nt*3+0]), a, 0,0,0);
                a = __builtin_amdgcn_mfma_f32_16x16x32_bf16(g1, u2b8(eF1[nt*3+1]), a, 0,0,0);
                a = __builtin_amdgcn_mfma_f32_16x16x32_bf16(g2, u2b8(eF1[nt*3+2]), a, 0,0,0);
                if (quad == 0){
                    u16t v = f2b(a[0]);
                    Actx[aaddr(nt*16+col, wv*2+1)] = v;
                    Actx[aaddr(nt*16+col, wv*2+9)] = v;
                }
            }
        }
        bar_lds();

        // Phase C: comb = [emb|ctx] @ combW^T + b -> Acmb
        {
            bf16x8 ae0 = AeV[(0*4+quad)*16 + col],   ae1 = AeV[(1*4+quad)*16 + col];
            bf16x8 ax0 = ActxV[(0*4+quad)*16 + col], ax1 = ActxV[(1*4+quad)*16 + col];
            float bz = combB[wv*16 + col];
            f32x4 a; a[0]=bz; a[1]=bz; a[2]=bz; a[3]=bz;
            a = __builtin_amdgcn_mfma_f32_16x16x32_bf16(ae0, Bc[0], a, 0,0,0);
            a = __builtin_amdgcn_mfma_f32_16x16x32_bf16(ae1, Bc[1], a, 0,0,0);
            a = __builtin_amdgcn_mfma_f32_16x16x32_bf16(ax0, Bc[2], a, 0,0,0);
            a = __builtin_amdgcn_mfma_f32_16x16x32_bf16(ax1, Bc[3], a, 0,0,0);
            #pragma unroll
            for (int r = 0; r < 4; ++r)
                Acmb[aaddr(wv*16+col, quad*4 + r)] = f2b(a[r]);
        }
        bar_lds();

        // Phase D: dec LSTM gates via MFMA; nonlinear; h -> AhW (+dup)
        {
            bf16x8 ac0 = AcmbV[(0*4+quad)*16 + col], ac1 = AcmbV[(1*4+quad)*16 + col];
            bf16x8 ah0 = AhV[(0*4+quad)*16 + col],   ah1 = AhV[(1*4+quad)*16 + col];
            f32x4 g4[4];
            #pragma unroll
            for (int g = 0; g < 4; ++g){
                float bz = decB[g*64 + wv*16 + col];
                f32x4 a; a[0]=bz; a[1]=bz; a[2]=bz; a[3]=bz;
                a = __builtin_amdgcn_mfma_f32_16x16x32_bf16(ac0, Bd[g][0], a, 0,0,0);
                a = __builtin_amdgcn_mfma_f32_16x16x32_bf16(ac1, Bd[g][1], a, 0,0,0);
                a = __builtin_amdgcn_mfma_f32_16x16x32_bf16(ah0, Bd[g][2], a, 0,0,0);
                a = __builtin_amdgcn_mfma_f32_16x16x32_bf16(ah1, Bd[g][3], a, 0,0,0);
                g4[g] = a;
            }
            #pragma unroll
            for (int rr = 0; rr < 2; ++rr){
                int r = r0 + rr;
                int b = (quad*4 + r) & 7;
                float c = sigm(g4[1][r])*creg[rr] + sigm(g4[0][r])*tanh2(g4[2][r]);
                float h = sigm(g4[3][r])*tanh2(c);
                creg[rr] = c;
                u16t hv = f2b(h);
                AhW[aaddr(jmy, b)]   = hv;
                AhW[aaddr(jmy, b+8)] = hv;
            }
        }
        bar_lds();

        // Phase E: emb(t+1) = relu(h @ M1^T + b1) -> Ae (all waves);
        //          wave3 (light in Phase A): pred = h @ outW^T + outb -> outp
        {
            const bf16x8* AhWV = (const bf16x8*)AhW;
            bf16x8 xh0 = AhWV[(0*4+quad)*16 + col];
            bf16x8 xh1 = AhWV[(1*4+quad)*16 + col];
            bf16x8 m10 = *(const bf16x8*)&M1L[jmy*64 + ((quad ^ (jmy&7))<<3)];
            bf16x8 m11 = *(const bf16x8*)&M1L[jmy*64 + (((4+quad) ^ (jmy&7))<<3)];
            float eb = b1B[wv*16 + col];
            f32x4 a; a[0]=eb; a[1]=eb; a[2]=eb; a[3]=eb;
            a = __builtin_amdgcn_mfma_f32_16x16x32_bf16(xh0, m10, a, 0,0,0);
            a = __builtin_amdgcn_mfma_f32_16x16x32_bf16(xh1, m11, a, 0,0,0);
            #pragma unroll
            for (int r = 0; r < 4; ++r)
                Ae[aaddr(wv*16+col, quad*4 + r)] = f2b(fmaxf(a[r], 0.f));
            if (wv == 3){
                bf16x8 oBf0 = zz, oBf1 = zz;
                if (col < CC){
                    oBf0 = *(const bf16x8*)&oWL[col*64 + ((quad ^ col)<<3)];
                    oBf1 = *(const bf16x8*)&oWL[col*64 + (((4+quad) ^ col)<<3)];
                }
                float ob = outB[col & 7];
                f32x4 p4; p4[0]=ob; p4[1]=ob; p4[2]=ob; p4[3]=ob;
                p4 = __builtin_amdgcn_mfma_f32_16x16x32_bf16(xh0, oBf0, p4, 0,0,0);
                p4 = __builtin_amdgcn_mfma_f32_16x16x32_bf16(xh1, oBf1, p4, 0,0,0);
                if (col < CC){
                    #pragma unroll
                    for (int r = 0; r < 4; ++r){
                        int m = quad*4 + r;
                        if (m < 8)
                            stf<F32>(outp, ((size_t)(b0+m)*TT + t)*CC + col, p4[r] + slp[col*10 + m]);
                    }
                }
            }
        }
        bar_lds();
    }
}

// =============================================================================
// FALLBACK: the proven fused kernel (verbatim), used only if ws_size cannot
// hold eoG (50.33MB) + cG (1MB).
// =============================================================================
template<bool F32>
__global__ __launch_bounds__(256,2) void fused_g(
    const void* __restrict__ x_enc,
    const void* __restrict__ eWih, const void* __restrict__ eWhh,
    const void* __restrict__ ebih, const void* __restrict__ ebhh,
    const void* __restrict__ embW, const void* __restrict__ embb,
    const void* __restrict__ attnW, const void* __restrict__ attnb,
    const void* __restrict__ combW, const void* __restrict__ combb,
    const void* __restrict__ dWih, const void* __restrict__ dWhh,
    const void* __restrict__ dbih, const void* __restrict__ dbhh,
    const void* __restrict__ outW, const void* __restrict__ outb,
    void* __restrict__ outp, u16t* __restrict__ eoG)
{
    if (inputs_are_f32(ebih) != F32) return;

    __shared__ __align__(16) float slp[CC*10];
    __shared__ __align__(16) short Abuf2[2][1536];
    __shared__ __align__(16) char  uni[18880];

    const int tid = threadIdx.x;
    const int b0  = blockIdx.x * BT;
    const int col = tid & 15, quad = (tid >> 4) & 3, wv = tid >> 6;
    const int r0  = (quad >> 1) * 2;

    bf16x8 Bf[4][3];
    float  biasg[4];
    #pragma unroll
    for (int g = 0; g < 4; ++g){
        int r = g*64 + wv*16 + col;
        biasg[g] = ldf<F32>(ebih, r) + ldf<F32>(ebhh, r);
        #pragma unroll
        for (int kb = 0; kb < 3; ++kb){
            bf16x8 v;
            #pragma unroll
            for (int x = 0; x < 8; ++x){
                int k = kb*32 + quad*8 + x;
                v[x] = (short)f2b(ldW_enc<F32>(eWih, eWhh, r, k));
            }
            Bf[g][kb] = v;
        }
    }
    for (int n = tid; n < 2*1536; n += 256) ((short*)Abuf2)[n] = 0;
    float sl = 0.f; size_t xbase = 0;
    if (tid < BT*CC){ int b = tid >> 3, i = tid & 7;
        xbase = (size_t)(b0+b)*(LL*CC) + i;
        sl = ldf<F32>(x_enc, xbase + (size_t)(LL-1)*CC);
        slp[i*10 + b] = sl; }
    __syncthreads();
    if (tid < BT*CC){ short v = (short)f2b(ldf<F32>(x_enc, xbase) - sl);
        Abuf2[0][tid] = v; Abuf2[0][tid + 64] = v; }
    float xr = (tid < BT*CC) ? ldf<F32>(x_enc, xbase + CC) : 0.f;

    const int jmy = wv*16 + col;
    const int kh  = 8 + jmy;
    const int hwbase = aaddr(kh, 0);

    u32t ebase[2];
    #pragma unroll
    for (int rr = 0; rr < 2; ++rr){
        u32t bg = (u32t)(b0 + ((quad*4 + r0 + rr) & 7));
        ebase[rr] = (bg*4u + (u32t)(jmy>>4))*1536u + (u32t)((jmy&15)*8);
    }

    float creg[2] = {0.f,0.f};
    u16t  hb16[2] = {0,0};

    for (int t = 0; t < LL; ++t){
        __syncthreads();
        const bf16x8* AbR = (const bf16x8*)Abuf2[t & 1];
        short*        AbW = Abuf2[(t + 1) & 1];
        bf16x8 a0 = AbR[(0*4 + quad)*16 + col];
        bf16x8 a1 = AbR[(1*4 + quad)*16 + col];
        bf16x8 a2 = AbR[(2*4 + quad)*16 + col];
        f32x4 acc[4];
        #pragma unroll
        for (int g = 0; g < 4; ++g){
            f32x4 a; a[0]=biasg[g]; a[1]=biasg[g]; a[2]=biasg[g]; a[3]=biasg[g];
            a = __builtin_amdgcn_mfma_f32_16x16x32_bf16(a0, Bf[g][0], a, 0,0,0);
            a = __builtin_amdgcn_mfma_f32_16x16x32_bf16(a1, Bf[g][1], a, 0,0,0);
            a = __builtin_amdgcn_mfma_f32_16x16x32_bf16(a2, Bf[g][2], a, 0,0,0);
            acc[g] = a;
        }
        int off = (t>>5)*512 + ((t>>3)&3)*128 + (t&7);
        #pragma unroll
        for (int rr = 0; rr < 2; ++rr){
            int r = r0 + rr;
            int b = (quad*4 + r) & 7;
            float c = sigm(acc[1][r])*creg[rr] + sigm(acc[0][r])*tanh2(acc[2][r]);
            float h = sigm(acc[3][r])*tanh2(c);
            creg[rr] = c; hb16[rr] = f2b(h);
            eoG[ebase[rr] + off] = hb16[rr];
            AbW[hwbase + b*8]     = (short)hb16[rr];
            AbW[hwbase + (b+8)*8] = (short)hb16[rr];
        }
        if (tid < BT*CC && t < LL-1){
            short v = (short)f2b(xr - sl);
            AbW[tid] = v; AbW[tid + 64] = v;
            int tn = (t+2 < LL) ? t+2 : LL-1;
            xr = ldf<F32>(x_enc, xbase + (size_t)tn*CC);
        }
    }

    bf16x8 Bd[4][4];
    #pragma unroll
    for (int g = 0; g < 4; ++g){
        int r = g*64 + wv*16 + col;
        Bd[g][0] = u2b8(ld8p<F32>(dWih, (size_t)r*HH + quad*8));
        Bd[g][1] = u2b8(ld8p<F32>(dWih, (size_t)r*HH + 32 + quad*8));
        Bd[g][2] = u2b8(ld8p<F32>(dWhh, (size_t)r*HH + quad*8));
        Bd[g][3] = u2b8(ld8p<F32>(dWhh, (size_t)r*HH + 32 + quad*8));
    }
    bf16x8 Ba[2][4];
    #pragma unroll
    for (int kb = 0; kb < 4; ++kb)
        Ba[0][kb] = u2b8(ld8p<F32>(attnW, (size_t)(wv*16+col)*128 + kb*32 + quad*8));
    if (wv < 2){
        #pragma unroll
        for (int kb = 0; kb < 4; ++kb)
            Ba[1][kb] = u2b8(ld8p<F32>(attnW, (size_t)((4+wv)*16+col)*128 + kb*32 + quad*8));
    } else {
        #pragma unroll
        for (int kb = 0; kb < 4; ++kb) Ba[1][kb] = Ba[0][kb];
    }
    bf16x8 Bc[4];
    #pragma unroll
    for (int kb = 0; kb < 4; ++kb)
        Bc[kb] = u2b8(ld8p<F32>(combW, (size_t)(wv*16+col)*128 + kb*32 + quad*8));
    bf16x8 zz = {0,0,0,0,0,0,0,0};
    bf16x8 eBf = zz;
    if (quad == 0) eBf = u2b8(ld8p<F32>(embW, (size_t)(wv*16+col)*CC));
    bf16x8 oBf0 = zz, oBf1 = zz;
    if (col < CC){
        oBf0 = u2b8(ld8p<F32>(outW, (size_t)col*HH + quad*8));
        oBf1 = u2b8(ld8p<F32>(outW, (size_t)col*HH + 32 + quad*8));
    }

    float* decB  = (float*)(uni + 0);
    float* attnB = (float*)(uni + 1024);
    float* embB  = (float*)(uni + 1408);
    float* combB = (float*)(uni + 1664);
    float* outB  = (float*)(uni + 1920);
    float* Lg    = (float*)(uni + 1952);
    u16t*  awB   = (u16t*)(uni + 5024);
    u16t*  Ae    = (u16t*)(uni + 6560);
    u16t*  Ah0   = (u16t*)(uni + 8608);
    u16t*  Ah1   = (u16t*)(uni + 10656);
    u16t*  Actx  = (u16t*)(uni + 12704);
    u16t*  Acmb  = (u16t*)(uni + 14752);
    u16t*  Apred = (u16t*)(uni + 16800);

    #pragma unroll
    for (int rr = 0; rr < 2; ++rr){
        int b = (quad*4 + r0 + rr) & 7;
        Ah0[aaddr(jmy, b)]     = hb16[rr];
        Ah0[aaddr(jmy, b+8)]   = hb16[rr];
    }
    decB[tid] = ldf<F32>(dbih, tid) + ldf<F32>(dbhh, tid);
    if (tid < LL) attnB[tid] = ldf<F32>(attnb, tid);
    if (tid < HH) embB[tid]  = ldf<F32>(embb, tid);
    if (tid < HH) combB[tid] = ldf<F32>(combb, tid);
    if (tid < CC) outB[tid]  = ldf<F32>(outb, tid);
    for (int n = tid; n < 1024; n += 256) Apred[n] = 0;
    __syncthreads();

    const u16t* ebp = eoG + (size_t)(b0 + wv*2) * 6144;
    uint4 eF0[12], eF1[12];
    #pragma unroll
    for (int f = 0; f < 12; ++f) eF0[f] = *(const uint4*)(ebp + f*512 + quad*128 + col*8);
    #pragma unroll
    for (int f = 0; f < 12; ++f) eF1[f] = *(const uint4*)(ebp + 6144 + f*512 + quad*128 + col*8);

    const int lgS = tid & 31, bS = tid >> 5;
    const bf16x8* AeV   = (const bf16x8*)Ae;
    const bf16x8* ActxV = (const bf16x8*)Actx;
    const bf16x8* AcmbV = (const bf16x8*)Acmb;
    const bf16x8* ApV   = (const bf16x8*)Apred;

    for (int t = 0; t < TT; ++t){
        u16t* AhR = (t & 1) ? Ah1 : Ah0;
        u16t* AhW = (t & 1) ? Ah0 : Ah1;
        const bf16x8* AhV = (const bf16x8*)AhR;

        {
            bf16x8 ap = ApV[quad*16 + col];
            float eb = embB[wv*16 + col];
            f32x4 a; a[0]=eb; a[1]=eb; a[2]=eb; a[3]=eb;
            a = __builtin_amdgcn_mfma_f32_16x16x32_bf16(ap, eBf, a, 0,0,0);
            #pragma unroll
            for (int r = 0; r < 4; ++r)
                Ae[aaddr(wv*16+col, quad*4 + r)] = f2b(fmaxf(a[r], 0.f));
        }
        __syncthreads();

        {
            bf16x8 ae0 = AeV[(0*4+quad)*16 + col], ae1 = AeV[(1*4+quad)*16 + col];
            bf16x8 ah0 = AhV[(0*4+quad)*16 + col], ah1 = AhV[(1*4+quad)*16 + col];
            const int ns = (wv < 2) ? 2 : 1;
            for (int s = 0; s < ns; ++s){
                int lt = (s == 0) ? wv : 4+wv;
                float bz = attnB[lt*16 + col];
                f32x4 a; a[0]=bz; a[1]=bz; a[2]=bz; a[3]=bz;
                a = __builtin_amdgcn_mfma_f32_16x16x32_bf16(ae0, Ba[s][0], a, 0,0,0);
                a = __builtin_amdgcn_mfma_f32_16x16x32_bf16(ae1, Ba[s][1], a, 0,0,0);
                a = __builtin_amdgcn_mfma_f32_16x16x32_bf16(ah0, Ba[s][2], a, 0,0,0);
                a = __builtin_amdgcn_mfma_f32_16x16x32_bf16(ah1, Ba[s][3], a, 0,0,0);
                if (quad < 2)
                    *(float4*)&Lg[(lt*16+col)*8 + quad*4] = make_float4(a[0],a[1],a[2],a[3]);
            }
        }
        __syncthreads();

        {
            int l = lgS*3;
            float ev0 = Lg[l*8 + bS], ev1 = Lg[(l+1)*8 + bS], ev2 = Lg[(l+2)*8 + bS];
            float mx = fmaxf(ev0, fmaxf(ev1, ev2));
            #pragma unroll
            for (int m = 16; m >= 1; m >>= 1) mx = fmaxf(mx, __shfl_xor(mx, m, 32));
            float e0 = __expf(ev0 - mx), e1 = __expf(ev1 - mx), e2 = __expf(ev2 - mx);
            float sm = e0 + e1 + e2;
            #pragma unroll
            for (int m = 16; m >= 1; m >>= 1) sm += __shfl_xor(sm, m, 32);
            float inv = rcpf(sm);
            awB[bS*96 + l]     = f2b(e0*inv);
            awB[bS*96 + l + 1] = f2b(e1*inv);
            awB[bS*96 + l + 2] = f2b(e2*inv);
        }
        {
            const u16t* ap0 = awB + (wv*2)*96;
            bf16x8 f0 = *(const bf16x8*)(ap0 + quad*8);
            bf16x8 f1 = *(const bf16x8*)(ap0 + 32 + quad*8);
            bf16x8 f2 = *(const bf16x8*)(ap0 + 64 + quad*8);
            #pragma unroll
            for (int nt = 0; nt < 4; ++nt){
                f32x4 a; a[0]=0.f; a[1]=0.f; a[2]=0.f; a[3]=0.f;
                a = __builtin_amdgcn_mfma_f32_16x16x32_bf16(f0, u2b8(eF0[nt*3+0]), a, 0,0,0);
                a = __builtin_amdgcn_mfma_f32_16x16x32_bf16(f1, u2b8(eF0[nt*3+1]), a, 0,0,0);
                a = __builtin_amdgcn_mfma_f32_16x16x32_bf16(f2, u2b8(eF0[nt*3+2]), a, 0,0,0);
                if (quad == 0){
                    u16t v = f2b(a[0]);
                    Actx[aaddr(nt*16+col, wv*2)]   = v;
                    Actx[aaddr(nt*16+col, wv*2+8)] = v;
                }
            }
            const u16t* ap1 = awB + (wv*2+1)*96;
            bf16x8 g0 = *(const bf16x8*)(ap1 + quad*8);
            bf16x8 g1 = *(const bf16x8*)(ap1 + 32 + quad*8);
            bf16x8 g2 = *(const bf16x8*)(ap1 + 64 + quad*8);
            #pragma unroll
            for (int nt = 0; nt < 4; ++nt){
                f32x4 a; a[0]=0.f; a[1]=0.f; a[2]=0.f; a[3]=0.f;
                a = __builtin_amdgcn_mfma_f32_16x16x32_bf16(g0, u2b8(eF1[nt*3+0]), a, 0,0,0);
                a = __builtin_amdgcn_mfma_f32_16x16x32_bf16(g1, u2b8(eF1[nt*3+1]), a, 0,0,0);
                a = __builtin_amdgcn_mfma_f32_16x16x32_bf16(g2, u2b8(eF1[nt*3+2]), a, 0,0,0);
                if (quad == 0){
                    u16t v = f2b(a[0]);
                    Actx[aaddr(nt*16+col, wv*2+1)] = v;
                    Actx[aaddr(nt*16+col, wv*2+9)] = v;
                }
            }
        }
        __syncthreads();

        {
            bf16x8 ae0 = AeV[(0*4+quad)*16 + col],   ae1 = AeV[(1*4+quad)*16 + col];
            bf16x8 ax0 = ActxV[(0*4+quad)*16 + col], ax1 = ActxV[(1*4+quad)*16 + col];
            float bz = combB[wv*16 + col];
            f32x4 a; a[0]=bz; a[1]=bz; a[2]=bz; a[3]=bz;
            a = __builtin_amdgcn_mfma_f32_16x16x32_bf16(ae0, Bc[0], a, 0,0,0);
            a = __builtin_amdgcn_mfma_f32_16x16x32_bf16(ae1, Bc[1], a, 0,0,0);
            a = __builtin_amdgcn_mfma_f32_16x16x32_bf16(ax0, Bc[2], a, 0,0,0);
            a = __builtin_amdgcn_mfma_f32_16x16x32_bf16(ax1, Bc[3], a, 0,0,0);
            #pragma unroll
            for (int r = 0; r < 4; ++r)
                Acmb[aaddr(wv*16+col, quad*4 + r)] = f2b(a[r]);
        }
        __syncthreads();

        {
            bf16x8 ac0 = AcmbV[(0*4+quad)*16 + col], ac1 = AcmbV[(1*4+quad)*16 + col];
            bf16x8 ah0 = AhV[(0*4+quad)*16 + col],   ah1 = AhV[(1*4+quad)*16 + col];
            f32x4 g4[4];
            #pragma unroll
            for (int g = 0; g < 4; ++g){
                float bz = decB[g*64 + wv*16 + col];
                f32x4 a; a[0]=bz; a[1]=bz; a[2]=bz; a[3]=bz;
                a = __builtin_amdgcn_mfma_f32_16x16x32_bf16(ac0, Bd[g][0], a, 0,0,0);
                a = __builtin_amdgcn_mfma_f32_16x16x32_bf16(ac1, Bd[g][1], a, 0,0,0);
                a = __builtin_amdgcn_mfma_f32_16x16x32_bf16(ah0, Bd[g][2], a, 0,0,0);
                a = __builtin_amdgcn_mfma_f32_16x16x32_bf16(ah1, Bd[g][3], a, 0,0,0);
                g4[g] = a;
            }
            #pragma unroll
            for (int rr = 0; rr < 2; ++rr){
                int r = r0 + rr;
                int b = (quad*4 + r) & 7;
                float c = sigm(g4[1][r])*creg[rr] + sigm(g4[0][r])*tanh2(g4[2][r]);
                float h = sigm(g4[3][r])*tanh2(c);
                creg[rr] = c;
                u16t hv = f2b(h);
                AhW[aaddr(jmy, b)]   = hv;
                AhW[aaddr(jmy, b+8)] = hv;
            }
        }
        __syncthreads();

        if (wv == 0){
            const bf16x8* AhWV = (const bf16x8*)AhW;
            bf16x8 xh0 = AhWV[(0*4+quad)*16 + col];
            bf16x8 xh1 = AhWV[(1*4+quad)*16 + col];
            float ob = outB[col & 7];
            f32x4 a; a[0]=ob; a[1]=ob; a[2]=ob; a[3]=ob;
            a = __builtin_amdgcn_mfma_f32_16x16x32_bf16(xh0, oBf0, a, 0,0,0);
            a = __builtin_amdgcn_mfma_f32_16x16x32_bf16(xh1, oBf1, a, 0,0,0);
            if (col < CC){
                #pragma unroll
                for (int r = 0; r < 4; ++r){
                    int m = quad*4 + r, b = m & 7;
                    float p = a[r];
                    Apred[aaddr(col, m)] = f2b(p);
                    if (m < 8)
                        stf<F32>(outp, ((size_t)(b0+b)*TT + t)*CC + col, p + slp[col*10 + b]);
                }
            }
        }
        __syncthreads();
    }
}

// --------------------------------------------------------------- launch -----
extern "C" void kernel_launch(void* const* d_in, const int* in_sizes, int n_in,
                              void* d_out, int out_size, void* d_ws, size_t ws_size,
                              hipStream_t stream)
{
    (void)out_size;
    // Host-side dtype dispatch: ebih (d_in[6]) has 256 elements -> 512B (bf16)
    // or 1024B (f32). If in_sizes is ambiguous (element counts / missing),
    // launch both templates (device-side probe guards correctness).
    bool doBF = true, doF32 = true;
    if (in_sizes && n_in > 6){
        if (in_sizes[6] == 512)  doF32 = false;
        else if (in_sizes[6] == 1024) doBF = false;
    }
    // eoG: 4096*96*64*2B = 50,331,648 B.  cG (f32 c-state): 4096*64*4B = 1,048,576 B.
    u16t* eoG = (u16t*)d_ws;
    if (ws_size >= 50331648ull + 1048576ull){
        float* cG = (float*)((char*)d_ws + 50331648ull);
        if (doBF){
            // encoder: BT=8, 512 blocks -> 2 blocks/CU, 2 waves/SIMD
            enc8_g<false><<<512, 256, 0, stream>>>(
                d_in[0], d_in[4], d_in[5], d_in[6], d_in[7], eoG, cG);
            dec8_g<false><<<NB, 256, 0, stream>>>(
                d_in[0],
                d_in[8],  d_in[9],  d_in[10], d_in[11],
                d_in[12], d_in[13], d_in[14], d_in[15],
                d_in[16], d_in[17], d_in[18], d_in[19],
                d_out, eoG, cG);
        }
        if (doF32){
            enc8_g<true ><<<512, 256, 0, stream>>>(
                d_in[0], d_in[4], d_in[5], d_in[6], d_in[7], eoG, cG);
            dec8_g<true ><<<NB, 256, 0, stream>>>(
                d_in[0],
                d_in[8],  d_in[9],  d_in[10], d_in[11],
                d_in[12], d_in[13], d_in[14], d_in[15],
                d_in[16], d_in[17], d_in[18], d_in[19],
                d_out, eoG, cG);
        }
    } else {
        // fallback: proven fused kernel (ws only fits eoG)
        if (doBF)
            fused_g<false><<<NB, 256, 0, stream>>>(
                d_in[0],
                d_in[4],  d_in[5],  d_in[6],  d_in[7],
                d_in[8],  d_in[9],  d_in[10], d_in[11],
                d_in[12], d_in[13], d_in[14], d_in[15],
                d_in[16], d_in[17], d_in[18], d_in[19],
                d_out, eoG);
        if (doF32)
            fused_g<true><<<NB, 256, 0, stream>>>(
                d_in[0],
                d_in[4],  d_in[5],  d_in[6],  d_in[7],
                d_in[8],  d_in[9],  d_in[10], d_in[11],
                d_in[12], d_in[13], d_in[14], d_in[15],
                d_in[16], d_in[17], d_in[18], d_in[19],
                d_out, eoG);
    }
}

// Round 9
// 260.069 us; speedup vs baseline: 1.0233x; 1.0233x over previous
//
#include <hip/hip_runtime.h>

#define LL 96
#define TT 24
#define HH 64
#define CC 8
#define GG 256   // 4*H
#define BT 8     // batches per block (decoder / fallback)
#define NB 512   // 4096/BT

typedef unsigned short u16t;
typedef unsigned int   u32t;
typedef __attribute__((ext_vector_type(8))) short bf16x8;
typedef __attribute__((ext_vector_type(4))) float f32x4;

__device__ __forceinline__ float b2f(u16t u){ union{u32t i; float f;} v; v.i=((u32t)u)<<16; return v.f; }
__device__ __forceinline__ u16t f2b(float f){ union{float f; u32t i;} v; v.f=f; u32t l=(v.i>>16)&1u; v.i+=0x7fffu+l; return (u16t)(v.i>>16); }
__device__ __forceinline__ float rcpf(float x){ return __builtin_amdgcn_rcpf(x); }
// fast sigmoid/tanh: v_exp + v_rcp (1-ulp), no precise-div chains
__device__ __forceinline__ float sigm(float x){ return rcpf(1.f + __expf(-x)); }
__device__ __forceinline__ float tanh2(float x){ return 1.f - 2.f*rcpf(__expf(2.f*x) + 1.f); }
// R9: clamped Pade(7,6) rational tanh — no exp on the chain; |err| <= 2.5e-4
// (boundary x=4.5: 0.99980 vs tanh 0.99975), an order below bf16's 4e-3 step.
// Swaps chained exp->rcp latency for 3 chained FMA + 1 rcp on the c->h link.
__device__ __forceinline__ float tanh_r(float x){
    float xc = fminf(fmaxf(x, -4.5f), 4.5f);
    float x2 = xc*xc;
    float np = ((x2 + 378.f)*x2 + 17325.f)*x2 + 135135.f;
    float dp = ((28.f*x2 + 3150.f)*x2 + 62370.f)*x2 + 135135.f;
    return xc*np*rcpf(dp);
}
__device__ __forceinline__ u32t pk2(float a, float b){ return (u32t)f2b(a) | ((u32t)f2b(b)<<16); }
__device__ __forceinline__ bf16x8 u2b8(uint4 u){ union{uint4 a; bf16x8 b;} v; v.a=u; return v.b; }
// A-layout slot (k, m): [kb][quad][m=16][x=8] shorts
__device__ __forceinline__ int aaddr(int k, int m){ return (((k>>5)*4 + ((k>>3)&3))*16 + m)*8 + (k&7); }

// LDS-only barrier: orders DS ops across the workgroup WITHOUT draining vmcnt.
__device__ __forceinline__ void bar_lds(){
    asm volatile("s_waitcnt lgkmcnt(0)" ::: "memory");
    __builtin_amdgcn_s_barrier();
    asm volatile("" ::: "memory");
    __builtin_amdgcn_sched_barrier(0);
}

// ---- dtype-agnostic load/store helpers --------------------------------------
template<bool F32> __device__ __forceinline__ float ldf(const void* p, size_t i){
    if constexpr (F32) return ((const float*)p)[i];
    else               return b2f(((const u16t*)p)[i]);
}
template<bool F32> __device__ __forceinline__ uint4 ld8p(const void* p, size_t i){
    if constexpr (F32){
        const float* f = (const float*)p + i;
        uint4 r; r.x = pk2(f[0],f[1]); r.y = pk2(f[2],f[3]);
                 r.z = pk2(f[4],f[5]); r.w = pk2(f[6],f[7]);
        return r;
    } else return *(const uint4*)((const u16t*)p + i);
}
template<bool F32> __device__ __forceinline__ void stf(void* p, size_t i, float v){
    if constexpr (F32) ((float*)p)[i] = v;
    else               ((u16t*)p)[i] = f2b(v);
}
template<bool F32> __device__ __forceinline__ float ldW_enc(const void* wih, const void* whh, int r, int k){
    if (k < CC)      return ldf<F32>(wih, (size_t)r*CC + k);
    else if (k < 72) return ldf<F32>(whh, (size_t)r*HH + (k-CC));
    else             return 0.f;
}

// dtype probe (bf16 confirmed live; kept as insurance — host dispatch via
// in_sizes normally launches only the matching template)
__device__ __forceinline__ bool inputs_are_f32(const void* bih){
    const u16t* p = (const u16t*)bih;
    int cnt = 0;
    #pragma unroll
    for (int i = 0; i < 64; ++i){
        u32t e = ((u32t)p[i] >> 7) & 0xFFu;
        cnt += (e >= 128u) ? 1 : 0;
    }
    return cnt > 0;
}

// =============================================================================
// Kernel 1 (R9): encoder BT=16, 256 blocks (1 block/CU) — R7 config (best of
// the occupancy scan: enc4=2330, enc8=2175, enc16=1850 cy/step; more waves =
// slower => serial-chain-bound, barrier irreducible). R9 change: tanh via
// clamped rational (tanh_r) to shorten the cross-step transcendental chain.
// =============================================================================
template<bool F32>
__global__ __launch_bounds__(256,1) void enc16_g(
    const void* __restrict__ x_enc,
    const void* __restrict__ eWih, const void* __restrict__ eWhh,
    const void* __restrict__ ebih, const void* __restrict__ ebhh,
    u16t* __restrict__ eoG, float* __restrict__ cG)
{
    if (inputs_are_f32(ebih) != F32) return;

    __shared__ __align__(16) short Abuf2[2][1536];

    const int tid = threadIdx.x;
    const int b0  = blockIdx.x * 16;
    const int col = tid & 15, quad = (tid >> 4) & 3, wv = tid >> 6;

    // encoder B-fragments + bias in registers
    bf16x8 Bf[4][3];
    float  biasg[4];
    #pragma unroll
    for (int g = 0; g < 4; ++g){
        int r = g*64 + wv*16 + col;
        biasg[g] = ldf<F32>(ebih, r) + ldf<F32>(ebhh, r);
        #pragma unroll
        for (int kb = 0; kb < 3; ++kb){
            bf16x8 v;
            #pragma unroll
            for (int x = 0; x < 8; ++x){
                int k = kb*32 + quad*8 + x;
                v[x] = (short)f2b(ldW_enc<F32>(eWih, eWhh, r, k));
            }
            Bf[g][kb] = v;
        }
    }
    for (int n = tid; n < 2*1536; n += 256) ((short*)Abuf2)[n] = 0;
    float sl = 0.f; size_t xbase = 0;
    if (tid < 128){ int b = tid >> 3, i = tid & 7;
        xbase = (size_t)(b0+b)*(LL*CC) + i;
        sl = ldf<F32>(x_enc, xbase + (size_t)(LL-1)*CC);
    }
    __syncthreads();
    // x(0): aaddr(i, b) == b*8+i == tid for i<8 -> single linear store, no dups
    if (tid < 128) Abuf2[0][tid] = (short)f2b(ldf<F32>(x_enc, xbase) - sl);
    float xr = (tid < 128) ? ldf<F32>(x_enc, xbase + CC) : 0.f;

    const int jmy = wv*16 + col;
    const int hwb = aaddr(8 + jmy, 0);
    u32t ebase[4];
    #pragma unroll
    for (int r = 0; r < 4; ++r)
        ebase[r] = ((u32t)(b0 + quad*4 + r)*4u + (u32t)(jmy>>4))*1536u + (u32t)((jmy&15)*8);

    float creg[4] = {0.f,0.f,0.f,0.f};
    u32t  pkv[4]  = {0,0,0,0};

    #pragma unroll 2
    for (int t = 0; t < LL; ++t){
        bar_lds();
        const bf16x8* AbR = (const bf16x8*)Abuf2[t & 1];
        short*        AbW = Abuf2[(t + 1) & 1];
        bf16x8 a0 = AbR[(0*4 + quad)*16 + col];
        bf16x8 a1 = AbR[(1*4 + quad)*16 + col];
        bf16x8 a2 = AbR[(2*4 + quad)*16 + col];
        f32x4 acc[4];
        #pragma unroll
        for (int g = 0; g < 4; ++g){
            f32x4 a; a[0]=biasg[g]; a[1]=biasg[g]; a[2]=biasg[g]; a[3]=biasg[g];
            a = __builtin_amdgcn_mfma_f32_16x16x32_bf16(a0, Bf[g][0], a, 0,0,0);
            a = __builtin_amdgcn_mfma_f32_16x16x32_bf16(a1, Bf[g][1], a, 0,0,0);
            a = __builtin_amdgcn_mfma_f32_16x16x32_bf16(a2, Bf[g][2], a, 0,0,0);
            acc[g] = a;
        }
        int off = (t>>5)*512 + ((t>>3)&3)*128 + (t&7);
        // FOUR elements per lane: batch = quad*4 + r (all C rows real), h=jmy
        #pragma unroll
        for (int r = 0; r < 4; ++r){
            float c = sigm(acc[1][r])*creg[r] + sigm(acc[0][r])*tanh_r(acc[2][r]);
            float h = sigm(acc[3][r])*tanh_r(c);
            creg[r] = c;
            u16t hb = f2b(h);
            if ((t & 1) == 0) pkv[r] = hb;
            else {
                pkv[r] |= ((u32t)hb) << 16;
                *(u32t*)&eoG[ebase[r] + (u32t)(off - 1)] = pkv[r];
            }
            AbW[hwb + (quad*4 + r)*8] = (short)hb;     // h -> next A-buf, row m=batch
        }
        if (tid < 128 && t < LL-1){
            AbW[tid] = (short)f2b(xr - sl);            // x(t+1), rows = 16 batches
            int tn = (t+2 < LL) ? t+2 : LL-1;
            xr = ldf<F32>(x_enc, xbase + (size_t)tn*CC);
        }
    }
    #pragma unroll
    for (int r = 0; r < 4; ++r)
        cG[(size_t)(b0 + quad*4 + r)*HH + jmy] = creg[r];
}

// =============================================================================
// Kernel 2: decoder, BT=8, 512 blocks. (R6 verbatim — parked: ~2000 cy/phase
// structural floor; conflicts off critical path, register cliff blocks
// occupancy. Regime is issue+barrier, so tanh_r not applied here.)
// =============================================================================
template<bool F32>
__global__ __launch_bounds__(256,2) void dec8_g(
    const void* __restrict__ x_enc,
    const void* __restrict__ embW, const void* __restrict__ embb,
    const void* __restrict__ attnW, const void* __restrict__ attnb,
    const void* __restrict__ combW, const void* __restrict__ combb,
    const void* __restrict__ dWih, const void* __restrict__ dWhh,
    const void* __restrict__ dbih, const void* __restrict__ dbhh,
    const void* __restrict__ outW, const void* __restrict__ outb,
    void* __restrict__ outp, const u16t* __restrict__ eoG,
    const float* __restrict__ cG)
{
    if (inputs_are_f32(dbih) != F32) return;

    __shared__ __align__(16) float slp[CC*10];
    __shared__ __align__(16) char  uni[17184];
    __shared__ __align__(16) u16t BaL[6*4*4*16*8];  // attnW frags: 24576B
    __shared__ __align__(16) u16t M1L[64*64];       // M1 = embW@outW, chunk-swizzled: 8192B
    __shared__ __align__(16) u16t oWL[8*64];        // outW, chunk-swizzled: 1024B

    const int tid = threadIdx.x;
    const int b0  = blockIdx.x * BT;
    const int col = tid & 15, quad = (tid >> 4) & 3, wv = tid >> 6;
    const int r0  = (quad >> 1) * 2;
    const int jmy = wv*16 + col;

    if (tid < BT*CC){ int b = tid >> 3, i = tid & 7;
        slp[i*10 + b] = ldf<F32>(x_enc, (size_t)(b0+b)*(LL*CC) + (size_t)(LL-1)*CC + i); }

    // ---------------- persistent register fragments (Bd, Bc) ----------------
    bf16x8 Bd[4][4];
    #pragma unroll
    for (int g = 0; g < 4; ++g){
        int r = g*64 + wv*16 + col;
        Bd[g][0] = u2b8(ld8p<F32>(dWih, (size_t)r*HH + quad*8));
        Bd[g][1] = u2b8(ld8p<F32>(dWih, (size_t)r*HH + 32 + quad*8));
        Bd[g][2] = u2b8(ld8p<F32>(dWhh, (size_t)r*HH + quad*8));
        Bd[g][3] = u2b8(ld8p<F32>(dWhh, (size_t)r*HH + 32 + quad*8));
    }
    bf16x8 Bc[4];
    #pragma unroll
    for (int kb = 0; kb < 4; ++kb)
        Bc[kb] = u2b8(ld8p<F32>(combW, (size_t)(wv*16+col)*128 + kb*32 + quad*8));
    bf16x8 zz = {0,0,0,0,0,0,0,0};

    // ---------------- LDS weight tables fill --------------------------------
    // attnW -> BaL, slot idx = lt*256 + kb*64 + quad*16 + col
    for (int idx = tid; idx < 1536; idx += 256){
        int lt_ = idx >> 8, kb_ = (idx >> 6) & 3, q_ = (idx >> 4) & 3, c_ = idx & 15;
        int row = lt_*16 + c_;
        u16t tmp[8];
        #pragma unroll
        for (int x = 0; x < 8; ++x)
            tmp[x] = f2b(ldf<F32>(attnW, (size_t)row*128 + kb_*32 + q_*8 + x));
        *(uint4*)&BaL[(size_t)idx*8] = *(uint4*)tmp;
    }
    // M1 = embW(64x8) @ outW(8x64), bf16, chunk-swizzled: elem (j,k) stored at
    // j*64 + ((k>>3 ^ (j&7))<<3 | (k&7))
    for (int idx = tid; idx < 1024; idx += 256){
        int j = idx >> 4, k0 = (idx & 15) * 4;
        float acc4[4] = {0.f,0.f,0.f,0.f};
        #pragma unroll
        for (int c = 0; c < 8; ++c){
            float e = ldf<F32>(embW, (size_t)j*CC + c);
            #pragma unroll
            for (int kk = 0; kk < 4; ++kk)
                acc4[kk] += e * ldf<F32>(outW, (size_t)c*HH + k0 + kk);
        }
        u16t tmp[4];
        #pragma unroll
        for (int kk = 0; kk < 4; ++kk) tmp[kk] = f2b(acc4[kk]);
        int sw = (((k0 >> 3) ^ (j & 7)) << 3) | (k0 & 7);
        *(uint2*)&M1L[j*64 + sw] = *(uint2*)tmp;
    }
    // outW -> oWL, same chunk swizzle (row c = 0..7)
    for (int n = tid; n < 512; n += 256){
        int c = n >> 6, k = n & 63;
        int sw = (((k >> 3) ^ (c & 7)) << 3) | (k & 7);
        oWL[c*64 + sw] = f2b(ldf<F32>(outW, n));
    }

    // ---------------- decoder LDS views + init ----------------
    float* decB  = (float*)(uni + 0);      // 256 f
    float* attnB = (float*)(uni + 1024);   // 96 f
    float* b1B   = (float*)(uni + 1408);   // 64 f : embb + embW@outb
    float* combB = (float*)(uni + 1664);   // 64 f
    float* outB  = (float*)(uni + 1920);   // 8 f
    float* Lg    = (float*)(uni + 1952);   // logits [l][9] stride-9 (3456B)
    u16t*  awB   = (u16t*)(uni + 5408);    // aw bf16 [b][96]
    u16t*  Ae    = (u16t*)(uni + 6944);    // emb A-buf
    u16t*  Ah0   = (u16t*)(uni + 8992);    // h A-buf ping
    u16t*  Ah1   = (u16t*)(uni + 11040);   // h A-buf pong
    u16t*  Actx  = (u16t*)(uni + 13088);   // ctx A-buf
    u16t*  Acmb  = (u16t*)(uni + 15136);   // comb A-buf

    float creg[2];
    #pragma unroll
    for (int rr = 0; rr < 2; ++rr){
        int b = (quad*4 + r0 + rr) & 7;
        // h(95) from eoG: off(95) = 2*512 + 3*128 + 7
        u16t hv = eoG[(((size_t)(b0+b)*4 + (size_t)(jmy>>4))*3 + 2)*512 + 3*128 + (jmy&15)*8 + 7];
        Ah0[aaddr(jmy, b)]   = hv;
        Ah0[aaddr(jmy, b+8)] = hv;
        creg[rr] = cG[(size_t)(b0+b)*HH + jmy];
    }
    decB[tid] = ldf<F32>(dbih, tid) + ldf<F32>(dbhh, tid);
    if (tid < LL) attnB[tid] = ldf<F32>(attnb, tid);
    if (tid < HH){
        float s = ldf<F32>(embb, tid);
        #pragma unroll
        for (int c = 0; c < 8; ++c)
            s += ldf<F32>(embW, (size_t)tid*CC + c) * ldf<F32>(outb, c);
        b1B[tid] = s;
    }
    if (tid < HH) combB[tid] = ldf<F32>(combb, tid);
    if (tid < CC) outB[tid]  = ldf<F32>(outb, tid);
    // Ae(0) = relu(embb) for all M rows (pred(-1) == 0 exactly)
    {
        float e0v = fmaxf(ldf<F32>(embb, jmy), 0.f);
        u16t ev = f2b(e0v);
        #pragma unroll
        for (int r = 0; r < 4; ++r)
            Ae[aaddr(jmy, quad*4 + r)] = ev;
    }
    __syncthreads();

    // eoG fragments for this wave's 2 batches -> registers
    const u16t* ebp = eoG + (size_t)(b0 + wv*2) * 6144;
    uint4 eF0[12], eF1[12];
    #pragma unroll
    for (int f = 0; f < 12; ++f) eF0[f] = *(const uint4*)(ebp + f*512 + quad*128 + col*8);
    #pragma unroll
    for (int f = 0; f < 12; ++f) eF1[f] = *(const uint4*)(ebp + 6144 + f*512 + quad*128 + col*8);

    const int lgS = tid & 31, bS = tid >> 5;
    const bf16x8* AeV   = (const bf16x8*)Ae;
    const bf16x8* ActxV = (const bf16x8*)Actx;
    const bf16x8* AcmbV = (const bf16x8*)Acmb;

    for (int t = 0; t < TT; ++t){
        u16t* AhR = (t & 1) ? Ah1 : Ah0;
        u16t* AhW = (t & 1) ? Ah0 : Ah1;
        const bf16x8* AhV = (const bf16x8*)AhR;

        // Phase A: attention logits via MFMA (Ba frags from LDS) -> Lg
        {
            bf16x8 ae0 = AeV[(0*4+quad)*16 + col], ae1 = AeV[(1*4+quad)*16 + col];
            bf16x8 ah0 = AhV[(0*4+quad)*16 + col], ah1 = AhV[(1*4+quad)*16 + col];
            const int ns = (wv < 2) ? 2 : 1;
            for (int s = 0; s < ns; ++s){
                int lt = (s == 0) ? wv : 4+wv;
                const u16t* bp = &BaL[lt*2048 + quad*128 + col*8];
                float bz = attnB[lt*16 + col];
                f32x4 a; a[0]=bz; a[1]=bz; a[2]=bz; a[3]=bz;
                a = __builtin_amdgcn_mfma_f32_16x16x32_bf16(ae0, *(const bf16x8*)&bp[0],    a, 0,0,0);
                a = __builtin_amdgcn_mfma_f32_16x16x32_bf16(ae1, *(const bf16x8*)&bp[512],  a, 0,0,0);
                a = __builtin_amdgcn_mfma_f32_16x16x32_bf16(ah0, *(const bf16x8*)&bp[1024], a, 0,0,0);
                a = __builtin_amdgcn_mfma_f32_16x16x32_bf16(ah1, *(const bf16x8*)&bp[1536], a, 0,0,0);
                if (quad < 2){
                    int rb = (lt*16+col)*9 + quad*4;
                    Lg[rb+0] = a[0]; Lg[rb+1] = a[1]; Lg[rb+2] = a[2]; Lg[rb+3] = a[3];
                }
            }
        }
        bar_lds();

        // Phase B: softmax (no max-subtract; logits bounded) + ctx MFMA
        {
            int l = lgS*3;
            float e0 = __expf(Lg[l*9 + bS]), e1 = __expf(Lg[(l+1)*9 + bS]), e2 = __expf(Lg[(l+2)*9 + bS]);
            float sm = e0 + e1 + e2;
            #pragma unroll
            for (int m = 16; m >= 1; m >>= 1) sm += __shfl_xor(sm, m, 32);
            float inv = rcpf(sm);
            awB[bS*96 + l]     = f2b(e0*inv);
            awB[bS*96 + l + 1] = f2b(e1*inv);
            awB[bS*96 + l + 2] = f2b(e2*inv);
        }
        // ctx via MFMA (A = aw broadcast, B = register eo frags); intra-wave RAW
        {
            const u16t* ap0 = awB + (wv*2)*96;
            bf16x8 f0 = *(const bf16x8*)(ap0 + quad*8);
            bf16x8 f1 = *(const bf16x8*)(ap0 + 32 + quad*8);
            bf16x8 f2 = *(const bf16x8*)(ap0 + 64 + quad*8);
            #pragma unroll
            for (int nt = 0; nt < 4; ++nt){
                f32x4 a; a[0]=0.f; a[1]=0.f; a[2]=0.f; a[3]=0.f;
                a = __builtin_amdgcn_mfma_f32_16x16x32_bf16(f0, u2b8(eF0[nt*3+0]), a, 0,0,0);
                a = __builtin_amdgcn_mfma_f32_16x16x32_bf16(f1, u2b8(eF0[nt*3+1]), a, 0,0,0);
                a = __builtin_amdgcn_mfma_f32_16x16x32_bf16(f2, u2b8(eF0[nt*3+2]), a, 0,0,0);
                if (quad == 0){
                    u16t v = f2b(a[0]);
                    Actx[aaddr(nt*16+col, wv*2)]   = v;
                    Actx[aaddr(nt*16+col, wv*2+8)] = v;
                }
            }
            const u16t* ap1 = awB + (wv*2+1)*96;
            bf16x8 g0 = *(const bf16x8*)(ap1 + quad*8);
            bf16x8 g1 = *(const bf16x8*)(ap1 + 32 + quad*8);
            bf16x8 g2 = *(const bf16x8*)(ap1 + 64 + quad*8);
            #pragma unroll
            for (int nt = 0; nt < 4; ++nt){
                f32x4 a; a[0]=0.f; a[1]=0.f; a[2]=0.f; a[3]=0.f;
                a = __builtin_amdgcn_mfma_f32_16x16x32_bf16(g0, u2b8(eF1[nt*3+0]), a, 0,0,0);
                a = __builtin_amdgcn_mfma_f32_16x16x32_bf16(g1, u2b8(eF1[nt*3+1]), a, 0,0,0);
                a = __builtin_amdgcn_mfma_f32_16x16x32_bf16(g2, u2b8(eF1[nt*3+2]), a, 0,0,0);
                if (quad == 0){
                    u16t v = f2b(a[0]);
                    Actx[aaddr(nt*16+col, wv*2+1)] = v;
                    Actx[aaddr(nt*16+col, wv*2+9)] = v;
                }
            }
        }
        bar_lds();

        // Phase C: comb = [emb|ctx] @ combW^T + b -> Acmb
        {
            bf16x8 ae0 = AeV[(0*4+quad)*16 + col],   ae1 = AeV[(1*4+quad)*16 + col];
            bf16x8 ax0 = ActxV[(0*4+quad)*16 + col], ax1 = ActxV[(1*4+quad)*16 + col];
            float bz = combB[wv*16 + col];
            f32x4 a; a[0]=bz; a[1]=bz; a[2]=bz; a[3]=bz;
            a = __builtin_amdgcn_mfma_f32_16x16x32_bf16(ae0, Bc[0], a, 0,0,0);
            a = __builtin_amdgcn_mfma_f32_16x16x32_bf16(ae1, Bc[1], a, 0,0,0);
            a = __builtin_amdgcn_mfma_f32_16x16x32_bf16(ax0, Bc[2], a, 0,0,0);
            a = __builtin_amdgcn_mfma_f32_16x16x32_bf16(ax1, Bc[3], a, 0,0,0);
            #pragma unroll
            for (int r = 0; r < 4; ++r)
                Acmb[aaddr(wv*16+col, quad*4 + r)] = f2b(a[r]);
        }
        bar_lds();

        // Phase D: dec LSTM gates via MFMA; nonlinear; h -> AhW (+dup)
        {
            bf16x8 ac0 = AcmbV[(0*4+quad)*16 + col], ac1 = AcmbV[(1*4+quad)*16 + col];
            bf16x8 ah0 = AhV[(0*4+quad)*16 + col],   ah1 = AhV[(1*4+quad)*16 + col];
            f32x4 g4[4];
            #pragma unroll
            for (int g = 0; g < 4; ++g){
                float bz = decB[g*64 + wv*16 + col];
                f32x4 a; a[0]=bz; a[1]=bz; a[2]=bz; a[3]=bz;
                a = __builtin_amdgcn_mfma_f32_16x16x32_bf16(ac0, Bd[g][0], a, 0,0,0);
                a = __builtin_amdgcn_mfma_f32_16x16x32_bf16(ac1, Bd[g][1], a, 0,0,0);
                a = __builtin_amdgcn_mfma_f32_16x16x32_bf16(ah0, Bd[g][2], a, 0,0,0);
                a = __builtin_amdgcn_mfma_f32_16x16x32_bf16(ah1, Bd[g][3], a, 0,0,0);
                g4[g] = a;
            }
            #pragma unroll
            for (int rr = 0; rr < 2; ++rr){
                int r = r0 + rr;
                int b = (quad*4 + r) & 7;
                float c = sigm(g4[1][r])*creg[rr] + sigm(g4[0][r])*tanh2(g4[2][r]);
                float h = sigm(g4[3][r])*tanh2(c);
                creg[rr] = c;
                u16t hv = f2b(h);
                AhW[aaddr(jmy, b)]   = hv;
                AhW[aaddr(jmy, b+8)] = hv;
            }
        }
        bar_lds();

        // Phase E: emb(t+1) = relu(h @ M1^T + b1) -> Ae (all waves);
        //          wave3 (light in Phase A): pred = h @ outW^T + outb -> outp
        {
            const bf16x8* AhWV = (const bf16x8*)AhW;
            bf16x8 xh0 = AhWV[(0*4+quad)*16 + col];
            bf16x8 xh1 = AhWV[(1*4+quad)*16 + col];
            bf16x8 m10 = *(const bf16x8*)&M1L[jmy*64 + ((quad ^ (jmy&7))<<3)];
            bf16x8 m11 = *(const bf16x8*)&M1L[jmy*64 + (((4+quad) ^ (jmy&7))<<3)];
            float eb = b1B[wv*16 + col];
            f32x4 a; a[0]=eb; a[1]=eb; a[2]=eb; a[3]=eb;
            a = __builtin_amdgcn_mfma_f32_16x16x32_bf16(xh0, m10, a, 0,0,0);
            a = __builtin_amdgcn_mfma_f32_16x16x32_bf16(xh1, m11, a, 0,0,0);
            #pragma unroll
            for (int r = 0; r < 4; ++r)
                Ae[aaddr(wv*16+col, quad*4 + r)] = f2b(fmaxf(a[r], 0.f));
            if (wv == 3){
                bf16x8 oBf0 = zz, oBf1 = zz;
                if (col < CC){
                    oBf0 = *(const bf16x8*)&oWL[col*64 + ((quad ^ col)<<3)];
                    oBf1 = *(const bf16x8*)&oWL[col*64 + (((4+quad) ^ col)<<3)];
                }
                float ob = outB[col & 7];
                f32x4 p4; p4[0]=ob; p4[1]=ob; p4[2]=ob; p4[3]=ob;
                p4 = __builtin_amdgcn_mfma_f32_16x16x32_bf16(xh0, oBf0, p4, 0,0,0);
                p4 = __builtin_amdgcn_mfma_f32_16x16x32_bf16(xh1, oBf1, p4, 0,0,0);
                if (col < CC){
                    #pragma unroll
                    for (int r = 0; r < 4; ++r){
                        int m = quad*4 + r;
                        if (m < 8)
                            stf<F32>(outp, ((size_t)(b0+m)*TT + t)*CC + col, p4[r] + slp[col*10 + m]);
                    }
                }
            }
        }
        bar_lds();
    }
}

// =============================================================================
// FALLBACK: the proven fused kernel (verbatim), used only if ws_size cannot
// hold eoG (50.33MB) + cG (1MB).
// =============================================================================
template<bool F32>
__global__ __launch_bounds__(256,2) void fused_g(
    const void* __restrict__ x_enc,
    const void* __restrict__ eWih, const void* __restrict__ eWhh,
    const void* __restrict__ ebih, const void* __restrict__ ebhh,
    const void* __restrict__ embW, const void* __restrict__ embb,
    const void* __restrict__ attnW, const void* __restrict__ attnb,
    const void* __restrict__ combW, const void* __restrict__ combb,
    const void* __restrict__ dWih, const void* __restrict__ dWhh,
    const void* __restrict__ dbih, const void* __restrict__ dbhh,
    const void* __restrict__ outW, const void* __restrict__ outb,
    void* __restrict__ outp, u16t* __restrict__ eoG)
{
    if (inputs_are_f32(ebih) != F32) return;

    __shared__ __align__(16) float slp[CC*10];
    __shared__ __align__(16) short Abuf2[2][1536];
    __shared__ __align__(16) char  uni[18880];

    const int tid = threadIdx.x;
    const int b0  = blockIdx.x * BT;
    const int col = tid & 15, quad = (tid >> 4) & 3, wv = tid >> 6;
    const int r0  = (quad >> 1) * 2;

    bf16x8 Bf[4][3];
    float  biasg[4];
    #pragma unroll
    for (int g = 0; g < 4; ++g){
        int r = g*64 + wv*16 + col;
        biasg[g] = ldf<F32>(ebih, r) + ldf<F32>(ebhh, r);
        #pragma unroll
        for (int kb = 0; kb < 3; ++kb){
            bf16x8 v;
            #pragma unroll
            for (int x = 0; x < 8; ++x){
                int k = kb*32 + quad*8 + x;
                v[x] = (short)f2b(ldW_enc<F32>(eWih, eWhh, r, k));
            }
            Bf[g][kb] = v;
        }
    }
    for (int n = tid; n < 2*1536; n += 256) ((short*)Abuf2)[n] = 0;
    float sl = 0.f; size_t xbase = 0;
    if (tid < BT*CC){ int b = tid >> 3, i = tid & 7;
        xbase = (size_t)(b0+b)*(LL*CC) + i;
        sl = ldf<F32>(x_enc, xbase + (size_t)(LL-1)*CC);
        slp[i*10 + b] = sl; }
    __syncthreads();
    if (tid < BT*CC){ short v = (short)f2b(ldf<F32>(x_enc, xbase) - sl);
        Abuf2[0][tid] = v; Abuf2[0][tid + 64] = v; }
    float xr = (tid < BT*CC) ? ldf<F32>(x_enc, xbase + CC) : 0.f;

    const int jmy = wv*16 + col;
    const int kh  = 8 + jmy;
    const int hwbase = aaddr(kh, 0);

    u32t ebase[2];
    #pragma unroll
    for (int rr = 0; rr < 2; ++rr){
        u32t bg = (u32t)(b0 + ((quad*4 + r0 + rr) & 7));
        ebase[rr] = (bg*4u + (u32t)(jmy>>4))*1536u + (u32t)((jmy&15)*8);
    }

    float creg[2] = {0.f,0.f};
    u16t  hb16[2] = {0,0};

    for (int t = 0; t < LL; ++t){
        __syncthreads();
        const bf16x8* AbR = (const bf16x8*)Abuf2[t & 1];
        short*        AbW = Abuf2[(t + 1) & 1];
        bf16x8 a0 = AbR[(0*4 + quad)*16 + col];
        bf16x8 a1 = AbR[(1*4 + quad)*16 + col];
        bf16x8 a2 = AbR[(2*4 + quad)*16 + col];
        f32x4 acc[4];
        #pragma unroll
        for (int g = 0; g < 4; ++g){
            f32x4 a; a[0]=biasg[g]; a[1]=biasg[g]; a[2]=biasg[g]; a[3]=biasg[g];
            a = __builtin_amdgcn_mfma_f32_16x16x32_bf16(a0, Bf[g][0], a, 0,0,0);
            a = __builtin_amdgcn_mfma_f32_16x16x32_bf16(a1, Bf[g][1], a, 0,0,0);
            a = __builtin_amdgcn_mfma_f32_16x16x32_bf16(a2, Bf[g][2], a, 0,0,0);
            acc[g] = a;
        }
        int off = (t>>5)*512 + ((t>>3)&3)*128 + (t&7);
        #pragma unroll
        for (int rr = 0; rr < 2; ++rr){
            int r = r0 + rr;
            int b = (quad*4 + r) & 7;
            float c = sigm(acc[1][r])*creg[rr] + sigm(acc[0][r])*tanh2(acc[2][r]);
            float h = sigm(acc[3][r])*tanh2(c);
            creg[rr] = c; hb16[rr] = f2b(h);
            eoG[ebase[rr] + off] = hb16[rr];
            AbW[hwbase + b*8]     = (short)hb16[rr];
            AbW[hwbase + (b+8)*8] = (short)hb16[rr];
        }
        if (tid < BT*CC && t < LL-1){
            short v = (short)f2b(xr - sl);
            AbW[tid] = v; AbW[tid + 64] = v;
            int tn = (t+2 < LL) ? t+2 : LL-1;
            xr = ldf<F32>(x_enc, xbase + (size_t)tn*CC);
        }
    }

    bf16x8 Bd[4][4];
    #pragma unroll
    for (int g = 0; g < 4; ++g){
        int r = g*64 + wv*16 + col;
        Bd[g][0] = u2b8(ld8p<F32>(dWih, (size_t)r*HH + quad*8));
        Bd[g][1] = u2b8(ld8p<F32>(dWih, (size_t)r*HH + 32 + quad*8));
        Bd[g][2] = u2b8(ld8p<F32>(dWhh, (size_t)r*HH + quad*8));
        Bd[g][3] = u2b8(ld8p<F32>(dWhh, (size_t)r*HH + 32 + quad*8));
    }
    bf16x8 Ba[2][4];
    #pragma unroll
    for (int kb = 0; kb < 4; ++kb)
        Ba[0][kb] = u2b8(ld8p<F32>(attnW, (size_t)(wv*16+col)*128 + kb*32 + quad*8));
    if (wv < 2){
        #pragma unroll
        for (int kb = 0; kb < 4; ++kb)
            Ba[1][kb] = u2b8(ld8p<F32>(attnW, (size_t)((4+wv)*16+col)*128 + kb*32 + quad*8));
    } else {
        #pragma unroll
        for (int kb = 0; kb < 4; ++kb) Ba[1][kb] = Ba[0][kb];
    }
    bf16x8 Bc[4];
    #pragma unroll
    for (int kb = 0; kb < 4; ++kb)
        Bc[kb] = u2b8(ld8p<F32>(combW, (size_t)(wv*16+col)*128 + kb*32 + quad*8));
    bf16x8 zz = {0,0,0,0,0,0,0,0};
    bf16x8 eBf = zz;
    if (quad == 0) eBf = u2b8(ld8p<F32>(embW, (size_t)(wv*16+col)*CC));
    bf16x8 oBf0 = zz, oBf1 = zz;
    if (col < CC){
        oBf0 = u2b8(ld8p<F32>(outW, (size_t)col*HH + quad*8));
        oBf1 = u2b8(ld8p<F32>(outW, (size_t)col*HH + 32 + quad*8));
    }

    float* decB  = (float*)(uni + 0);
    float* attnB = (float*)(uni + 1024);
    float* embB  = (float*)(uni + 1408);
    float* combB = (float*)(uni + 1664);
    float* outB  = (float*)(uni + 1920);
    float* Lg    = (float*)(uni + 1952);
    u16t*  awB   = (u16t*)(uni + 5024);
    u16t*  Ae    = (u16t*)(uni + 6560);
    u16t*  Ah0   = (u16t*)(uni + 8608);
    u16t*  Ah1   = (u16t*)(uni + 10656);
    u16t*  Actx  = (u16t*)(uni + 12704);
    u16t*  Acmb  = (u16t*)(uni + 14752);
    u16t*  Apred = (u16t*)(uni + 16800);

    #pragma unroll
    for (int rr = 0; rr < 2; ++rr){
        int b = (quad*4 + r0 + rr) & 7;
        Ah0[aaddr(jmy, b)]     = hb16[rr];
        Ah0[aaddr(jmy, b+8)]   = hb16[rr];
    }
    decB[tid] = ldf<F32>(dbih, tid) + ldf<F32>(dbhh, tid);
    if (tid < LL) attnB[tid] = ldf<F32>(attnb, tid);
    if (tid < HH) embB[tid]  = ldf<F32>(embb, tid);
    if (tid < HH) combB[tid] = ldf<F32>(combb, tid);
    if (tid < CC) outB[tid]  = ldf<F32>(outb, tid);
    for (int n = tid; n < 1024; n += 256) Apred[n] = 0;
    __syncthreads();

    const u16t* ebp = eoG + (size_t)(b0 + wv*2) * 6144;
    uint4 eF0[12], eF1[12];
    #pragma unroll
    for (int f = 0; f < 12; ++f) eF0[f] = *(const uint4*)(ebp + f*512 + quad*128 + col*8);
    #pragma unroll
    for (int f = 0; f < 12; ++f) eF1[f] = *(const uint4*)(ebp + 6144 + f*512 + quad*128 + col*8);

    const int lgS = tid & 31, bS = tid >> 5;
    const bf16x8* AeV   = (const bf16x8*)Ae;
    const bf16x8* ActxV = (const bf16x8*)Actx;
    const bf16x8* AcmbV = (const bf16x8*)Acmb;
    const bf16x8* ApV   = (const bf16x8*)Apred;

    for (int t = 0; t < TT; ++t){
        u16t* AhR = (t & 1) ? Ah1 : Ah0;
        u16t* AhW = (t & 1) ? Ah0 : Ah1;
        const bf16x8* AhV = (const bf16x8*)AhR;

        {
            bf16x8 ap = ApV[quad*16 + col];
            float eb = embB[wv*16 + col];
            f32x4 a; a[0]=eb; a[1]=eb; a[2]=eb; a[3]=eb;
            a = __builtin_amdgcn_mfma_f32_16x16x32_bf16(ap, eBf, a, 0,0,0);
            #pragma unroll
            for (int r = 0; r < 4; ++r)
                Ae[aaddr(wv*16+col, quad*4 + r)] = f2b(fmaxf(a[r], 0.f));
        }
        __syncthreads();

        {
            bf16x8 ae0 = AeV[(0*4+quad)*16 + col], ae1 = AeV[(1*4+quad)*16 + col];
            bf16x8 ah0 = AhV[(0*4+quad)*16 + col], ah1 = AhV[(1*4+quad)*16 + col];
            const int ns = (wv < 2) ? 2 : 1;
            for (int s = 0; s < ns; ++s){
                int lt = (s == 0) ? wv : 4+wv;
                float bz = attnB[lt*16 + col];
                f32x4 a; a[0]=bz; a[1]=bz; a[2]=bz; a[3]=bz;
                a = __builtin_amdgcn_mfma_f32_16x16x32_bf16(ae0, Ba[s][0], a, 0,0,0);
                a = __builtin_amdgcn_mfma_f32_16x16x32_bf16(ae1, Ba[s][1], a, 0,0,0);
                a = __builtin_amdgcn_mfma_f32_16x16x32_bf16(ah0, Ba[s][2], a, 0,0,0);
                a = __builtin_amdgcn_mfma_f32_16x16x32_bf16(ah1, Ba[s][3], a, 0,0,0);
                if (quad < 2)
                    *(float4*)&Lg[(lt*16+col)*8 + quad*4] = make_float4(a[0],a[1],a[2],a[3]);
            }
        }
        __syncthreads();

        {
            int l = lgS*3;
            float ev0 = Lg[l*8 + bS], ev1 = Lg[(l+1)*8 + bS], ev2 = Lg[(l+2)*8 + bS];
            float mx = fmaxf(ev0, fmaxf(ev1, ev2));
            #pragma unroll
            for (int m = 16; m >= 1; m >>= 1) mx = fmaxf(mx, __shfl_xor(mx, m, 32));
            float e0 = __expf(ev0 - mx), e1 = __expf(ev1 - mx), e2 = __expf(ev2 - mx);
            float sm = e0 + e1 + e2;
            #pragma unroll
            for (int m = 16; m >= 1; m >>= 1) sm += __shfl_xor(sm, m, 32);
            float inv = rcpf(sm);
            awB[bS*96 + l]     = f2b(e0*inv);
            awB[bS*96 + l + 1] = f2b(e1*inv);
            awB[bS*96 + l + 2] = f2b(e2*inv);
        }
        {
            const u16t* ap0 = awB + (wv*2)*96;
            bf16x8 f0 = *(const bf16x8*)(ap0 + quad*8);
            bf16x8 f1 = *(const bf16x8*)(ap0 + 32 + quad*8);
            bf16x8 f2 = *(const bf16x8*)(ap0 + 64 + quad*8);
            #pragma unroll
            for (int nt = 0; nt < 4; ++nt){
                f32x4 a; a[0]=0.f; a[1]=0.f; a[2]=0.f; a[3]=0.f;
                a = __builtin_amdgcn_mfma_f32_16x16x32_bf16(f0, u2b8(eF0[nt*3+0]), a, 0,0,0);
                a = __builtin_amdgcn_mfma_f32_16x16x32_bf16(f1, u2b8(eF0[nt*3+1]), a, 0,0,0);
                a = __builtin_amdgcn_mfma_f32_16x16x32_bf16(f2, u2b8(eF0[nt*3+2]), a, 0,0,0);
                if (quad == 0){
                    u16t v = f2b(a[0]);
                    Actx[aaddr(nt*16+col, wv*2)]   = v;
                    Actx[aaddr(nt*16+col, wv*2+8)] = v;
                }
            }
            const u16t* ap1 = awB + (wv*2+1)*96;
            bf16x8 g0 = *(const bf16x8*)(ap1 + quad*8);
            bf16x8 g1 = *(const bf16x8*)(ap1 + 32 + quad*8);
            bf16x8 g2 = *(const bf16x8*)(ap1 + 64 + quad*8);
            #pragma unroll
            for (int nt = 0; nt < 4; ++nt){
                f32x4 a; a[0]=0.f; a[1]=0.f; a[2]=0.f; a[3]=0.f;
                a = __builtin_amdgcn_mfma_f32_16x16x32_bf16(g0, u2b8(eF1[nt*3+0]), a, 0,0,0);
                a = __builtin_amdgcn_mfma_f32_16x16x32_bf16(g1, u2b8(eF1[nt*3+1]), a, 0,0,0);
                a = __builtin_amdgcn_mfma_f32_16x16x32_bf16(g2, u2b8(eF1[nt*3+2]), a, 0,0,0);
                if (quad == 0){
                    u16t v = f2b(a[0]);
                    Actx[aaddr(nt*16+col, wv*2+1)] = v;
                    Actx[aaddr(nt*16+col, wv*2+9)] = v;
                }
            }
        }
        __syncthreads();

        {
            bf16x8 ae0 = AeV[(0*4+quad)*16 + col],   ae1 = AeV[(1*4+quad)*16 + col];
            bf16x8 ax0 = ActxV[(0*4+quad)*16 + col], ax1 = ActxV[(1*4+quad)*16 + col];
            float bz = combB[wv*16 + col];
            f32x4 a; a[0]=bz; a[1]=bz; a[2]=bz; a[3]=bz;
            a = __builtin_amdgcn_mfma_f32_16x16x32_bf16(ae0, Bc[0], a, 0,0,0);
            a = __builtin_amdgcn_mfma_f32_16x16x32_bf16(ae1, Bc[1], a, 0,0,0);
            a = __builtin_amdgcn_mfma_f32_16x16x32_bf16(ax0, Bc[2], a, 0,0,0);
            a = __builtin_amdgcn_mfma_f32_16x16x32_bf16(ax1, Bc[3], a, 0,0,0);
            #pragma unroll
            for (int r = 0; r < 4; ++r)
                Acmb[aaddr(wv*16+col, quad*4 + r)] = f2b(a[r]);
        }
        __syncthreads();

        {
            bf16x8 ac0 = AcmbV[(0*4+quad)*16 + col], ac1 = AcmbV[(1*4+quad)*16 + col];
            bf16x8 ah0 = AhV[(0*4+quad)*16 + col],   ah1 = AhV[(1*4+quad)*16 + col];
            f32x4 g4[4];
            #pragma unroll
            for (int g = 0; g < 4; ++g){
                float bz = decB[g*64 + wv*16 + col];
                f32x4 a; a[0]=bz; a[1]=bz; a[2]=bz; a[3]=bz;
                a = __builtin_amdgcn_mfma_f32_16x16x32_bf16(ac0, Bd[g][0], a, 0,0,0);
                a = __builtin_amdgcn_mfma_f32_16x16x32_bf16(ac1, Bd[g][1], a, 0,0,0);
                a = __builtin_amdgcn_mfma_f32_16x16x32_bf16(ah0, Bd[g][2], a, 0,0,0);
                a = __builtin_amdgcn_mfma_f32_16x16x32_bf16(ah1, Bd[g][3], a, 0,0,0);
                g4[g] = a;
            }
            #pragma unroll
            for (int rr = 0; rr < 2; ++rr){
                int r = r0 + rr;
                int b = (quad*4 + r) & 7;
                float c = sigm(g4[1][r])*creg[rr] + sigm(g4[0][r])*tanh2(g4[2][r]);
                float h = sigm(g4[3][r])*tanh2(c);
                creg[rr] = c;
                u16t hv = f2b(h);
                AhW[aaddr(jmy, b)]   = hv;
                AhW[aaddr(jmy, b+8)] = hv;
            }
        }
        __syncthreads();

        if (wv == 0){
            const bf16x8* AhWV = (const bf16x8*)AhW;
            bf16x8 xh0 = AhWV[(0*4+quad)*16 + col];
            bf16x8 xh1 = AhWV[(1*4+quad)*16 + col];
            float ob = outB[col & 7];
            f32x4 a; a[0]=ob; a[1]=ob; a[2]=ob; a[3]=ob;
            a = __builtin_amdgcn_mfma_f32_16x16x32_bf16(xh0, oBf0, a, 0,0,0);
            a = __builtin_amdgcn_mfma_f32_16x16x32_bf16(xh1, oBf1, a, 0,0,0);
            if (col < CC){
                #pragma unroll
                for (int r = 0; r < 4; ++r){
                    int m = quad*4 + r, b = m & 7;
                    float p = a[r];
                    Apred[aaddr(col, m)] = f2b(p);
                    if (m < 8)
                        stf<F32>(outp, ((size_t)(b0+b)*TT + t)*CC + col, p + slp[col*10 + b]);
                }
            }
        }
        __syncthreads();
    }
}

// --------------------------------------------------------------- launch -----
extern "C" void kernel_launch(void* const* d_in, const int* in_sizes, int n_in,
                              void* d_out, int out_size, void* d_ws, size_t ws_size,
                              hipStream_t stream)
{
    (void)out_size;
    // Host-side dtype dispatch: ebih (d_in[6]) has 256 elements -> 512B (bf16)
    // or 1024B (f32). If in_sizes is ambiguous (element counts / missing),
    // launch both templates (device-side probe guards correctness).
    bool doBF = true, doF32 = true;
    if (in_sizes && n_in > 6){
        if (in_sizes[6] == 512)  doF32 = false;
        else if (in_sizes[6] == 1024) doBF = false;
    }
    // eoG: 4096*96*64*2B = 50,331,648 B.  cG (f32 c-state): 4096*64*4B = 1,048,576 B.
    u16t* eoG = (u16t*)d_ws;
    if (ws_size >= 50331648ull + 1048576ull){
        float* cG = (float*)((char*)d_ws + 50331648ull);
        if (doBF){
            // encoder: BT=16, 256 blocks (1 block/CU), M rows all real
            enc16_g<false><<<256, 256, 0, stream>>>(
                d_in[0], d_in[4], d_in[5], d_in[6], d_in[7], eoG, cG);
            dec8_g<false><<<NB, 256, 0, stream>>>(
                d_in[0],
                d_in[8],  d_in[9],  d_in[10], d_in[11],
                d_in[12], d_in[13], d_in[14], d_in[15],
                d_in[16], d_in[17], d_in[18], d_in[19],
                d_out, eoG, cG);
        }
        if (doF32){
            enc16_g<true ><<<256, 256, 0, stream>>>(
                d_in[0], d_in[4], d_in[5], d_in[6], d_in[7], eoG, cG);
            dec8_g<true ><<<NB, 256, 0, stream>>>(
                d_in[0],
                d_in[8],  d_in[9],  d_in[10], d_in[11],
                d_in[12], d_in[13], d_in[14], d_in[15],
                d_in[16], d_in[17], d_in[18], d_in[19],
                d_out, eoG, cG);
        }
    } else {
        // fallback: proven fused kernel (ws only fits eoG)
        if (doBF)
            fused_g<false><<<NB, 256, 0, stream>>>(
                d_in[0],
                d_in[4],  d_in[5],  d_in[6],  d_in[7],
                d_in[8],  d_in[9],  d_in[10], d_in[11],
                d_in[12], d_in[13], d_in[14], d_in[15],
                d_in[16], d_in[17], d_in[18], d_in[19],
                d_out, eoG);
        if (doF32)
            fused_g<true><<<NB, 256, 0, stream>>>(
                d_in[0],
                d_in[4],  d_in[5],  d_in[6],  d_in[7],
                d_in[8],  d_in[9],  d_in[10], d_in[11],
                d_in[12], d_in[13], d_in[14], d_in[15],
                d_in[16], d_in[17], d_in[18], d_in[19],
                d_out, eoG);
    }
}

// Round 10
// 252.615 us; speedup vs baseline: 1.0535x; 1.0295x over previous
//
#include <hip/hip_runtime.h>

#define LL 96
#define TT 24
#define HH 64
#define CC 8
#define GG 256   // 4*H
#define BT 8     // batches per block (decoder / fallback)
#define NB 512   // 4096/BT

typedef unsigned short u16t;
typedef unsigned int   u32t;
typedef __attribute__((ext_vector_type(8))) short bf16x8;
typedef __attribute__((ext_vector_type(4))) float f32x4;

__device__ __forceinline__ float b2f(u16t u){ union{u32t i; float f;} v; v.i=((u32t)u)<<16; return v.f; }
__device__ __forceinline__ u16t f2b(float f){ union{float f; u32t i;} v; v.f=f; u32t l=(v.i>>16)&1u; v.i+=0x7fffu+l; return (u16t)(v.i>>16); }
__device__ __forceinline__ float rcpf(float x){ return __builtin_amdgcn_rcpf(x); }
// fast sigmoid/tanh: v_exp + v_rcp (1-ulp), no precise-div chains.
// R9 post-mortem: rational (Pade) tanh measured SLOWER (+140cy/step) — equal
// dependency depth, +64cy issue. tanh2 is optimal; do not revisit.
__device__ __forceinline__ float sigm(float x){ return rcpf(1.f + __expf(-x)); }
__device__ __forceinline__ float tanh2(float x){ return 1.f - 2.f*rcpf(__expf(2.f*x) + 1.f); }
__device__ __forceinline__ u32t pk2(float a, float b){ return (u32t)f2b(a) | ((u32t)f2b(b)<<16); }
__device__ __forceinline__ bf16x8 u2b8(uint4 u){ union{uint4 a; bf16x8 b;} v; v.a=u; return v.b; }
// A-layout slot (k, m): [kb][quad][m=16][x=8] shorts
__device__ __forceinline__ int aaddr(int k, int m){ return (((k>>5)*4 + ((k>>3)&3))*16 + m)*8 + (k&7); }

// LDS-only barrier: orders DS ops across the workgroup WITHOUT draining vmcnt.
__device__ __forceinline__ void bar_lds(){
    asm volatile("s_waitcnt lgkmcnt(0)" ::: "memory");
    __builtin_amdgcn_s_barrier();
    asm volatile("" ::: "memory");
    __builtin_amdgcn_sched_barrier(0);
}

// ---- dtype-agnostic load/store helpers --------------------------------------
template<bool F32> __device__ __forceinline__ float ldf(const void* p, size_t i){
    if constexpr (F32) return ((const float*)p)[i];
    else               return b2f(((const u16t*)p)[i]);
}
template<bool F32> __device__ __forceinline__ uint4 ld8p(const void* p, size_t i){
    if constexpr (F32){
        const float* f = (const float*)p + i;
        uint4 r; r.x = pk2(f[0],f[1]); r.y = pk2(f[2],f[3]);
                 r.z = pk2(f[4],f[5]); r.w = pk2(f[6],f[7]);
        return r;
    } else return *(const uint4*)((const u16t*)p + i);
}
template<bool F32> __device__ __forceinline__ void stf(void* p, size_t i, float v){
    if constexpr (F32) ((float*)p)[i] = v;
    else               ((u16t*)p)[i] = f2b(v);
}
template<bool F32> __device__ __forceinline__ float ldW_enc(const void* wih, const void* whh, int r, int k){
    if (k < CC)      return ldf<F32>(wih, (size_t)r*CC + k);
    else if (k < 72) return ldf<F32>(whh, (size_t)r*HH + (k-CC));
    else             return 0.f;
}

// dtype probe (bf16 confirmed live; kept as insurance — host dispatch via
// in_sizes normally launches only the matching template)
__device__ __forceinline__ bool inputs_are_f32(const void* bih){
    const u16t* p = (const u16t*)bih;
    int cnt = 0;
    #pragma unroll
    for (int i = 0; i < 64; ++i){
        u32t e = ((u32t)p[i] >> 7) & 0xFFu;
        cnt += (e >= 128u) ? 1 : 0;
    }
    return cnt > 0;
}

// =============================================================================
// Kernel 1: encoder BT=16, 256 blocks (1 block/CU) — PROVEN best (R7: enc~74us).
// Occupancy scan measured: enc4(4w/SIMD)=2330, enc8(2w)=2175, enc16(1w)=1850
// cy/step -> serial-chain-bound, barrier irreducible (next step's A-fragment
// K-dim mixes h from all 4 waves). tanh2 (exp+rcp) beats rational tanh (R9).
// M=16 rows are 16 DISTINCT batches (no dup waste); all 4 C rows real.
// =============================================================================
template<bool F32>
__global__ __launch_bounds__(256,1) void enc16_g(
    const void* __restrict__ x_enc,
    const void* __restrict__ eWih, const void* __restrict__ eWhh,
    const void* __restrict__ ebih, const void* __restrict__ ebhh,
    u16t* __restrict__ eoG, float* __restrict__ cG)
{
    if (inputs_are_f32(ebih) != F32) return;

    __shared__ __align__(16) short Abuf2[2][1536];

    const int tid = threadIdx.x;
    const int b0  = blockIdx.x * 16;
    const int col = tid & 15, quad = (tid >> 4) & 3, wv = tid >> 6;

    // encoder B-fragments + bias in registers
    bf16x8 Bf[4][3];
    float  biasg[4];
    #pragma unroll
    for (int g = 0; g < 4; ++g){
        int r = g*64 + wv*16 + col;
        biasg[g] = ldf<F32>(ebih, r) + ldf<F32>(ebhh, r);
        #pragma unroll
        for (int kb = 0; kb < 3; ++kb){
            bf16x8 v;
            #pragma unroll
            for (int x = 0; x < 8; ++x){
                int k = kb*32 + quad*8 + x;
                v[x] = (short)f2b(ldW_enc<F32>(eWih, eWhh, r, k));
            }
            Bf[g][kb] = v;
        }
    }
    for (int n = tid; n < 2*1536; n += 256) ((short*)Abuf2)[n] = 0;
    float sl = 0.f; size_t xbase = 0;
    if (tid < 128){ int b = tid >> 3, i = tid & 7;
        xbase = (size_t)(b0+b)*(LL*CC) + i;
        sl = ldf<F32>(x_enc, xbase + (size_t)(LL-1)*CC);
    }
    __syncthreads();
    // x(0): aaddr(i, b) == b*8+i == tid for i<8 -> single linear store, no dups
    if (tid < 128) Abuf2[0][tid] = (short)f2b(ldf<F32>(x_enc, xbase) - sl);
    float xr = (tid < 128) ? ldf<F32>(x_enc, xbase + CC) : 0.f;

    const int jmy = wv*16 + col;
    const int hwb = aaddr(8 + jmy, 0);
    u32t ebase[4];
    #pragma unroll
    for (int r = 0; r < 4; ++r)
        ebase[r] = ((u32t)(b0 + quad*4 + r)*4u + (u32t)(jmy>>4))*1536u + (u32t)((jmy&15)*8);

    float creg[4] = {0.f,0.f,0.f,0.f};
    u32t  pkv[4]  = {0,0,0,0};

    #pragma unroll 2
    for (int t = 0; t < LL; ++t){
        bar_lds();
        const bf16x8* AbR = (const bf16x8*)Abuf2[t & 1];
        short*        AbW = Abuf2[(t + 1) & 1];
        bf16x8 a0 = AbR[(0*4 + quad)*16 + col];
        bf16x8 a1 = AbR[(1*4 + quad)*16 + col];
        bf16x8 a2 = AbR[(2*4 + quad)*16 + col];
        f32x4 acc[4];
        #pragma unroll
        for (int g = 0; g < 4; ++g){
            f32x4 a; a[0]=biasg[g]; a[1]=biasg[g]; a[2]=biasg[g]; a[3]=biasg[g];
            a = __builtin_amdgcn_mfma_f32_16x16x32_bf16(a0, Bf[g][0], a, 0,0,0);
            a = __builtin_amdgcn_mfma_f32_16x16x32_bf16(a1, Bf[g][1], a, 0,0,0);
            a = __builtin_amdgcn_mfma_f32_16x16x32_bf16(a2, Bf[g][2], a, 0,0,0);
            acc[g] = a;
        }
        int off = (t>>5)*512 + ((t>>3)&3)*128 + (t&7);
        // FOUR elements per lane: batch = quad*4 + r (all C rows real), h=jmy
        #pragma unroll
        for (int r = 0; r < 4; ++r){
            float c = sigm(acc[1][r])*creg[r] + sigm(acc[0][r])*tanh2(acc[2][r]);
            float h = sigm(acc[3][r])*tanh2(c);
            creg[r] = c;
            u16t hb = f2b(h);
            if ((t & 1) == 0) pkv[r] = hb;
            else {
                pkv[r] |= ((u32t)hb) << 16;
                *(u32t*)&eoG[ebase[r] + (u32t)(off - 1)] = pkv[r];
            }
            AbW[hwb + (quad*4 + r)*8] = (short)hb;     // h -> next A-buf, row m=batch
        }
        if (tid < 128 && t < LL-1){
            AbW[tid] = (short)f2b(xr - sl);            // x(t+1), rows = 16 batches
            int tn = (t+2 < LL) ? t+2 : LL-1;
            xr = ldf<F32>(x_enc, xbase + (size_t)tn*CC);
        }
    }
    #pragma unroll
    for (int r = 0; r < 4; ++r)
        cG[(size_t)(b0 + quad*4 + r)*HH + jmy] = creg[r];
}

// =============================================================================
// Kernel 2: decoder, BT=8, 512 blocks. (R6 form — structural floor: all 5
// barriers guard genuine cross-wave RAW deps; register cliff blocks occupancy;
// conflicts proven off critical path.)
// =============================================================================
template<bool F32>
__global__ __launch_bounds__(256,2) void dec8_g(
    const void* __restrict__ x_enc,
    const void* __restrict__ embW, const void* __restrict__ embb,
    const void* __restrict__ attnW, const void* __restrict__ attnb,
    const void* __restrict__ combW, const void* __restrict__ combb,
    const void* __restrict__ dWih, const void* __restrict__ dWhh,
    const void* __restrict__ dbih, const void* __restrict__ dbhh,
    const void* __restrict__ outW, const void* __restrict__ outb,
    void* __restrict__ outp, const u16t* __restrict__ eoG,
    const float* __restrict__ cG)
{
    if (inputs_are_f32(dbih) != F32) return;

    __shared__ __align__(16) float slp[CC*10];
    __shared__ __align__(16) char  uni[17184];
    __shared__ __align__(16) u16t BaL[6*4*4*16*8];  // attnW frags: 24576B
    __shared__ __align__(16) u16t M1L[64*64];       // M1 = embW@outW, chunk-swizzled: 8192B
    __shared__ __align__(16) u16t oWL[8*64];        // outW, chunk-swizzled: 1024B

    const int tid = threadIdx.x;
    const int b0  = blockIdx.x * BT;
    const int col = tid & 15, quad = (tid >> 4) & 3, wv = tid >> 6;
    const int r0  = (quad >> 1) * 2;
    const int jmy = wv*16 + col;

    if (tid < BT*CC){ int b = tid >> 3, i = tid & 7;
        slp[i*10 + b] = ldf<F32>(x_enc, (size_t)(b0+b)*(LL*CC) + (size_t)(LL-1)*CC + i); }

    // ---------------- persistent register fragments (Bd, Bc) ----------------
    bf16x8 Bd[4][4];
    #pragma unroll
    for (int g = 0; g < 4; ++g){
        int r = g*64 + wv*16 + col;
        Bd[g][0] = u2b8(ld8p<F32>(dWih, (size_t)r*HH + quad*8));
        Bd[g][1] = u2b8(ld8p<F32>(dWih, (size_t)r*HH + 32 + quad*8));
        Bd[g][2] = u2b8(ld8p<F32>(dWhh, (size_t)r*HH + quad*8));
        Bd[g][3] = u2b8(ld8p<F32>(dWhh, (size_t)r*HH + 32 + quad*8));
    }
    bf16x8 Bc[4];
    #pragma unroll
    for (int kb = 0; kb < 4; ++kb)
        Bc[kb] = u2b8(ld8p<F32>(combW, (size_t)(wv*16+col)*128 + kb*32 + quad*8));
    bf16x8 zz = {0,0,0,0,0,0,0,0};

    // ---------------- LDS weight tables fill --------------------------------
    // attnW -> BaL, slot idx = lt*256 + kb*64 + quad*16 + col
    for (int idx = tid; idx < 1536; idx += 256){
        int lt_ = idx >> 8, kb_ = (idx >> 6) & 3, q_ = (idx >> 4) & 3, c_ = idx & 15;
        int row = lt_*16 + c_;
        u16t tmp[8];
        #pragma unroll
        for (int x = 0; x < 8; ++x)
            tmp[x] = f2b(ldf<F32>(attnW, (size_t)row*128 + kb_*32 + q_*8 + x));
        *(uint4*)&BaL[(size_t)idx*8] = *(uint4*)tmp;
    }
    // M1 = embW(64x8) @ outW(8x64), bf16, chunk-swizzled: elem (j,k) stored at
    // j*64 + ((k>>3 ^ (j&7))<<3 | (k&7))
    for (int idx = tid; idx < 1024; idx += 256){
        int j = idx >> 4, k0 = (idx & 15) * 4;
        float acc4[4] = {0.f,0.f,0.f,0.f};
        #pragma unroll
        for (int c = 0; c < 8; ++c){
            float e = ldf<F32>(embW, (size_t)j*CC + c);
            #pragma unroll
            for (int kk = 0; kk < 4; ++kk)
                acc4[kk] += e * ldf<F32>(outW, (size_t)c*HH + k0 + kk);
        }
        u16t tmp[4];
        #pragma unroll
        for (int kk = 0; kk < 4; ++kk) tmp[kk] = f2b(acc4[kk]);
        int sw = (((k0 >> 3) ^ (j & 7)) << 3) | (k0 & 7);
        *(uint2*)&M1L[j*64 + sw] = *(uint2*)tmp;
    }
    // outW -> oWL, same chunk swizzle (row c = 0..7)
    for (int n = tid; n < 512; n += 256){
        int c = n >> 6, k = n & 63;
        int sw = (((k >> 3) ^ (c & 7)) << 3) | (k & 7);
        oWL[c*64 + sw] = f2b(ldf<F32>(outW, n));
    }

    // ---------------- decoder LDS views + init ----------------
    float* decB  = (float*)(uni + 0);      // 256 f
    float* attnB = (float*)(uni + 1024);   // 96 f
    float* b1B   = (float*)(uni + 1408);   // 64 f : embb + embW@outb
    float* combB = (float*)(uni + 1664);   // 64 f
    float* outB  = (float*)(uni + 1920);   // 8 f
    float* Lg    = (float*)(uni + 1952);   // logits [l][9] stride-9 (3456B)
    u16t*  awB   = (u16t*)(uni + 5408);    // aw bf16 [b][96]
    u16t*  Ae    = (u16t*)(uni + 6944);    // emb A-buf
    u16t*  Ah0   = (u16t*)(uni + 8992);    // h A-buf ping
    u16t*  Ah1   = (u16t*)(uni + 11040);   // h A-buf pong
    u16t*  Actx  = (u16t*)(uni + 13088);   // ctx A-buf
    u16t*  Acmb  = (u16t*)(uni + 15136);   // comb A-buf

    float creg[2];
    #pragma unroll
    for (int rr = 0; rr < 2; ++rr){
        int b = (quad*4 + r0 + rr) & 7;
        // h(95) from eoG: off(95) = 2*512 + 3*128 + 7
        u16t hv = eoG[(((size_t)(b0+b)*4 + (size_t)(jmy>>4))*3 + 2)*512 + 3*128 + (jmy&15)*8 + 7];
        Ah0[aaddr(jmy, b)]   = hv;
        Ah0[aaddr(jmy, b+8)] = hv;
        creg[rr] = cG[(size_t)(b0+b)*HH + jmy];
    }
    decB[tid] = ldf<F32>(dbih, tid) + ldf<F32>(dbhh, tid);
    if (tid < LL) attnB[tid] = ldf<F32>(attnb, tid);
    if (tid < HH){
        float s = ldf<F32>(embb, tid);
        #pragma unroll
        for (int c = 0; c < 8; ++c)
            s += ldf<F32>(embW, (size_t)tid*CC + c) * ldf<F32>(outb, c);
        b1B[tid] = s;
    }
    if (tid < HH) combB[tid] = ldf<F32>(combb, tid);
    if (tid < CC) outB[tid]  = ldf<F32>(outb, tid);
    // Ae(0) = relu(embb) for all M rows (pred(-1) == 0 exactly)
    {
        float e0v = fmaxf(ldf<F32>(embb, jmy), 0.f);
        u16t ev = f2b(e0v);
        #pragma unroll
        for (int r = 0; r < 4; ++r)
            Ae[aaddr(jmy, quad*4 + r)] = ev;
    }
    __syncthreads();

    // eoG fragments for this wave's 2 batches -> registers
    const u16t* ebp = eoG + (size_t)(b0 + wv*2) * 6144;
    uint4 eF0[12], eF1[12];
    #pragma unroll
    for (int f = 0; f < 12; ++f) eF0[f] = *(const uint4*)(ebp + f*512 + quad*128 + col*8);
    #pragma unroll
    for (int f = 0; f < 12; ++f) eF1[f] = *(const uint4*)(ebp + 6144 + f*512 + quad*128 + col*8);

    const int lgS = tid & 31, bS = tid >> 5;
    const bf16x8* AeV   = (const bf16x8*)Ae;
    const bf16x8* ActxV = (const bf16x8*)Actx;
    const bf16x8* AcmbV = (const bf16x8*)Acmb;

    for (int t = 0; t < TT; ++t){
        u16t* AhR = (t & 1) ? Ah1 : Ah0;
        u16t* AhW = (t & 1) ? Ah0 : Ah1;
        const bf16x8* AhV = (const bf16x8*)AhR;

        // Phase A: attention logits via MFMA (Ba frags from LDS) -> Lg
        {
            bf16x8 ae0 = AeV[(0*4+quad)*16 + col], ae1 = AeV[(1*4+quad)*16 + col];
            bf16x8 ah0 = AhV[(0*4+quad)*16 + col], ah1 = AhV[(1*4+quad)*16 + col];
            const int ns = (wv < 2) ? 2 : 1;
            for (int s = 0; s < ns; ++s){
                int lt = (s == 0) ? wv : 4+wv;
                const u16t* bp = &BaL[lt*2048 + quad*128 + col*8];
                float bz = attnB[lt*16 + col];
                f32x4 a; a[0]=bz; a[1]=bz; a[2]=bz; a[3]=bz;
                a = __builtin_amdgcn_mfma_f32_16x16x32_bf16(ae0, *(const bf16x8*)&bp[0],    a, 0,0,0);
                a = __builtin_amdgcn_mfma_f32_16x16x32_bf16(ae1, *(const bf16x8*)&bp[512],  a, 0,0,0);
                a = __builtin_amdgcn_mfma_f32_16x16x32_bf16(ah0, *(const bf16x8*)&bp[1024], a, 0,0,0);
                a = __builtin_amdgcn_mfma_f32_16x16x32_bf16(ah1, *(const bf16x8*)&bp[1536], a, 0,0,0);
                if (quad < 2){
                    int rb = (lt*16+col)*9 + quad*4;
                    Lg[rb+0] = a[0]; Lg[rb+1] = a[1]; Lg[rb+2] = a[2]; Lg[rb+3] = a[3];
                }
            }
        }
        bar_lds();

        // Phase B: softmax (no max-subtract; logits bounded) + ctx MFMA
        {
            int l = lgS*3;
            float e0 = __expf(Lg[l*9 + bS]), e1 = __expf(Lg[(l+1)*9 + bS]), e2 = __expf(Lg[(l+2)*9 + bS]);
            float sm = e0 + e1 + e2;
            #pragma unroll
            for (int m = 16; m >= 1; m >>= 1) sm += __shfl_xor(sm, m, 32);
            float inv = rcpf(sm);
            awB[bS*96 + l]     = f2b(e0*inv);
            awB[bS*96 + l + 1] = f2b(e1*inv);
            awB[bS*96 + l + 2] = f2b(e2*inv);
        }
        // ctx via MFMA (A = aw broadcast, B = register eo frags); intra-wave RAW
        {
            const u16t* ap0 = awB + (wv*2)*96;
            bf16x8 f0 = *(const bf16x8*)(ap0 + quad*8);
            bf16x8 f1 = *(const bf16x8*)(ap0 + 32 + quad*8);
            bf16x8 f2 = *(const bf16x8*)(ap0 + 64 + quad*8);
            #pragma unroll
            for (int nt = 0; nt < 4; ++nt){
                f32x4 a; a[0]=0.f; a[1]=0.f; a[2]=0.f; a[3]=0.f;
                a = __builtin_amdgcn_mfma_f32_16x16x32_bf16(f0, u2b8(eF0[nt*3+0]), a, 0,0,0);
                a = __builtin_amdgcn_mfma_f32_16x16x32_bf16(f1, u2b8(eF0[nt*3+1]), a, 0,0,0);
                a = __builtin_amdgcn_mfma_f32_16x16x32_bf16(f2, u2b8(eF0[nt*3+2]), a, 0,0,0);
                if (quad == 0){
                    u16t v = f2b(a[0]);
                    Actx[aaddr(nt*16+col, wv*2)]   = v;
                    Actx[aaddr(nt*16+col, wv*2+8)] = v;
                }
            }
            const u16t* ap1 = awB + (wv*2+1)*96;
            bf16x8 g0 = *(const bf16x8*)(ap1 + quad*8);
            bf16x8 g1 = *(const bf16x8*)(ap1 + 32 + quad*8);
            bf16x8 g2 = *(const bf16x8*)(ap1 + 64 + quad*8);
            #pragma unroll
            for (int nt = 0; nt < 4; ++nt){
                f32x4 a; a[0]=0.f; a[1]=0.f; a[2]=0.f; a[3]=0.f;
                a = __builtin_amdgcn_mfma_f32_16x16x32_bf16(g0, u2b8(eF1[nt*3+0]), a, 0,0,0);
                a = __builtin_amdgcn_mfma_f32_16x16x32_bf16(g1, u2b8(eF1[nt*3+1]), a, 0,0,0);
                a = __builtin_amdgcn_mfma_f32_16x16x32_bf16(g2, u2b8(eF1[nt*3+2]), a, 0,0,0);
                if (quad == 0){
                    u16t v = f2b(a[0]);
                    Actx[aaddr(nt*16+col, wv*2+1)] = v;
                    Actx[aaddr(nt*16+col, wv*2+9)] = v;
                }
            }
        }
        bar_lds();

        // Phase C: comb = [emb|ctx] @ combW^T + b -> Acmb
        {
            bf16x8 ae0 = AeV[(0*4+quad)*16 + col],   ae1 = AeV[(1*4+quad)*16 + col];
            bf16x8 ax0 = ActxV[(0*4+quad)*16 + col], ax1 = ActxV[(1*4+quad)*16 + col];
            float bz = combB[wv*16 + col];
            f32x4 a; a[0]=bz; a[1]=bz; a[2]=bz; a[3]=bz;
            a = __builtin_amdgcn_mfma_f32_16x16x32_bf16(ae0, Bc[0], a, 0,0,0);
            a = __builtin_amdgcn_mfma_f32_16x16x32_bf16(ae1, Bc[1], a, 0,0,0);
            a = __builtin_amdgcn_mfma_f32_16x16x32_bf16(ax0, Bc[2], a, 0,0,0);
            a = __builtin_amdgcn_mfma_f32_16x16x32_bf16(ax1, Bc[3], a, 0,0,0);
            #pragma unroll
            for (int r = 0; r < 4; ++r)
                Acmb[aaddr(wv*16+col, quad*4 + r)] = f2b(a[r]);
        }
        bar_lds();

        // Phase D: dec LSTM gates via MFMA; nonlinear; h -> AhW (+dup)
        {
            bf16x8 ac0 = AcmbV[(0*4+quad)*16 + col], ac1 = AcmbV[(1*4+quad)*16 + col];
            bf16x8 ah0 = AhV[(0*4+quad)*16 + col],   ah1 = AhV[(1*4+quad)*16 + col];
            f32x4 g4[4];
            #pragma unroll
            for (int g = 0; g < 4; ++g){
                float bz = decB[g*64 + wv*16 + col];
                f32x4 a; a[0]=bz; a[1]=bz; a[2]=bz; a[3]=bz;
                a = __builtin_amdgcn_mfma_f32_16x16x32_bf16(ac0, Bd[g][0], a, 0,0,0);
                a = __builtin_amdgcn_mfma_f32_16x16x32_bf16(ac1, Bd[g][1], a, 0,0,0);
                a = __builtin_amdgcn_mfma_f32_16x16x32_bf16(ah0, Bd[g][2], a, 0,0,0);
                a = __builtin_amdgcn_mfma_f32_16x16x32_bf16(ah1, Bd[g][3], a, 0,0,0);
                g4[g] = a;
            }
            #pragma unroll
            for (int rr = 0; rr < 2; ++rr){
                int r = r0 + rr;
                int b = (quad*4 + r) & 7;
                float c = sigm(g4[1][r])*creg[rr] + sigm(g4[0][r])*tanh2(g4[2][r]);
                float h = sigm(g4[3][r])*tanh2(c);
                creg[rr] = c;
                u16t hv = f2b(h);
                AhW[aaddr(jmy, b)]   = hv;
                AhW[aaddr(jmy, b+8)] = hv;
            }
        }
        bar_lds();

        // Phase E: emb(t+1) = relu(h @ M1^T + b1) -> Ae (all waves);
        //          wave3 (light in Phase A): pred = h @ outW^T + outb -> outp
        {
            const bf16x8* AhWV = (const bf16x8*)AhW;
            bf16x8 xh0 = AhWV[(0*4+quad)*16 + col];
            bf16x8 xh1 = AhWV[(1*4+quad)*16 + col];
            bf16x8 m10 = *(const bf16x8*)&M1L[jmy*64 + ((quad ^ (jmy&7))<<3)];
            bf16x8 m11 = *(const bf16x8*)&M1L[jmy*64 + (((4+quad) ^ (jmy&7))<<3)];
            float eb = b1B[wv*16 + col];
            f32x4 a; a[0]=eb; a[1]=eb; a[2]=eb; a[3]=eb;
            a = __builtin_amdgcn_mfma_f32_16x16x32_bf16(xh0, m10, a, 0,0,0);
            a = __builtin_amdgcn_mfma_f32_16x16x32_bf16(xh1, m11, a, 0,0,0);
            #pragma unroll
            for (int r = 0; r < 4; ++r)
                Ae[aaddr(wv*16+col, quad*4 + r)] = f2b(fmaxf(a[r], 0.f));
            if (wv == 3){
                bf16x8 oBf0 = zz, oBf1 = zz;
                if (col < CC){
                    oBf0 = *(const bf16x8*)&oWL[col*64 + ((quad ^ col)<<3)];
                    oBf1 = *(const bf16x8*)&oWL[col*64 + (((4+quad) ^ col)<<3)];
                }
                float ob = outB[col & 7];
                f32x4 p4; p4[0]=ob; p4[1]=ob; p4[2]=ob; p4[3]=ob;
                p4 = __builtin_amdgcn_mfma_f32_16x16x32_bf16(xh0, oBf0, p4, 0,0,0);
                p4 = __builtin_amdgcn_mfma_f32_16x16x32_bf16(xh1, oBf1, p4, 0,0,0);
                if (col < CC){
                    #pragma unroll
                    for (int r = 0; r < 4; ++r){
                        int m = quad*4 + r;
                        if (m < 8)
                            stf<F32>(outp, ((size_t)(b0+m)*TT + t)*CC + col, p4[r] + slp[col*10 + m]);
                    }
                }
            }
        }
        bar_lds();
    }
}

// =============================================================================
// FALLBACK: the proven fused kernel (verbatim), used only if ws_size cannot
// hold eoG (50.33MB) + cG (1MB).
// =============================================================================
template<bool F32>
__global__ __launch_bounds__(256,2) void fused_g(
    const void* __restrict__ x_enc,
    const void* __restrict__ eWih, const void* __restrict__ eWhh,
    const void* __restrict__ ebih, const void* __restrict__ ebhh,
    const void* __restrict__ embW, const void* __restrict__ embb,
    const void* __restrict__ attnW, const void* __restrict__ attnb,
    const void* __restrict__ combW, const void* __restrict__ combb,
    const void* __restrict__ dWih, const void* __restrict__ dWhh,
    const void* __restrict__ dbih, const void* __restrict__ dbhh,
    const void* __restrict__ outW, const void* __restrict__ outb,
    void* __restrict__ outp, u16t* __restrict__ eoG)
{
    if (inputs_are_f32(ebih) != F32) return;

    __shared__ __align__(16) float slp[CC*10];
    __shared__ __align__(16) short Abuf2[2][1536];
    __shared__ __align__(16) char  uni[18880];

    const int tid = threadIdx.x;
    const int b0  = blockIdx.x * BT;
    const int col = tid & 15, quad = (tid >> 4) & 3, wv = tid >> 6;
    const int r0  = (quad >> 1) * 2;

    bf16x8 Bf[4][3];
    float  biasg[4];
    #pragma unroll
    for (int g = 0; g < 4; ++g){
        int r = g*64 + wv*16 + col;
        biasg[g] = ldf<F32>(ebih, r) + ldf<F32>(ebhh, r);
        #pragma unroll
        for (int kb = 0; kb < 3; ++kb){
            bf16x8 v;
            #pragma unroll
            for (int x = 0; x < 8; ++x){
                int k = kb*32 + quad*8 + x;
                v[x] = (short)f2b(ldW_enc<F32>(eWih, eWhh, r, k));
            }
            Bf[g][kb] = v;
        }
    }
    for (int n = tid; n < 2*1536; n += 256) ((short*)Abuf2)[n] = 0;
    float sl = 0.f; size_t xbase = 0;
    if (tid < BT*CC){ int b = tid >> 3, i = tid & 7;
        xbase = (size_t)(b0+b)*(LL*CC) + i;
        sl = ldf<F32>(x_enc, xbase + (size_t)(LL-1)*CC);
        slp[i*10 + b] = sl; }
    __syncthreads();
    if (tid < BT*CC){ short v = (short)f2b(ldf<F32>(x_enc, xbase) - sl);
        Abuf2[0][tid] = v; Abuf2[0][tid + 64] = v; }
    float xr = (tid < BT*CC) ? ldf<F32>(x_enc, xbase + CC) : 0.f;

    const int jmy = wv*16 + col;
    const int kh  = 8 + jmy;
    const int hwbase = aaddr(kh, 0);

    u32t ebase[2];
    #pragma unroll
    for (int rr = 0; rr < 2; ++rr){
        u32t bg = (u32t)(b0 + ((quad*4 + r0 + rr) & 7));
        ebase[rr] = (bg*4u + (u32t)(jmy>>4))*1536u + (u32t)((jmy&15)*8);
    }

    float creg[2] = {0.f,0.f};
    u16t  hb16[2] = {0,0};

    for (int t = 0; t < LL; ++t){
        __syncthreads();
        const bf16x8* AbR = (const bf16x8*)Abuf2[t & 1];
        short*        AbW = Abuf2[(t + 1) & 1];
        bf16x8 a0 = AbR[(0*4 + quad)*16 + col];
        bf16x8 a1 = AbR[(1*4 + quad)*16 + col];
        bf16x8 a2 = AbR[(2*4 + quad)*16 + col];
        f32x4 acc[4];
        #pragma unroll
        for (int g = 0; g < 4; ++g){
            f32x4 a; a[0]=biasg[g]; a[1]=biasg[g]; a[2]=biasg[g]; a[3]=biasg[g];
            a = __builtin_amdgcn_mfma_f32_16x16x32_bf16(a0, Bf[g][0], a, 0,0,0);
            a = __builtin_amdgcn_mfma_f32_16x16x32_bf16(a1, Bf[g][1], a, 0,0,0);
            a = __builtin_amdgcn_mfma_f32_16x16x32_bf16(a2, Bf[g][2], a, 0,0,0);
            acc[g] = a;
        }
        int off = (t>>5)*512 + ((t>>3)&3)*128 + (t&7);
        #pragma unroll
        for (int rr = 0; rr < 2; ++rr){
            int r = r0 + rr;
            int b = (quad*4 + r) & 7;
            float c = sigm(acc[1][r])*creg[rr] + sigm(acc[0][r])*tanh2(acc[2][r]);
            float h = sigm(acc[3][r])*tanh2(c);
            creg[rr] = c; hb16[rr] = f2b(h);
            eoG[ebase[rr] + off] = hb16[rr];
            AbW[hwbase + b*8]     = (short)hb16[rr];
            AbW[hwbase + (b+8)*8] = (short)hb16[rr];
        }
        if (tid < BT*CC && t < LL-1){
            short v = (short)f2b(xr - sl);
            AbW[tid] = v; AbW[tid + 64] = v;
            int tn = (t+2 < LL) ? t+2 : LL-1;
            xr = ldf<F32>(x_enc, xbase + (size_t)tn*CC);
        }
    }

    bf16x8 Bd[4][4];
    #pragma unroll
    for (int g = 0; g < 4; ++g){
        int r = g*64 + wv*16 + col;
        Bd[g][0] = u2b8(ld8p<F32>(dWih, (size_t)r*HH + quad*8));
        Bd[g][1] = u2b8(ld8p<F32>(dWih, (size_t)r*HH + 32 + quad*8));
        Bd[g][2] = u2b8(ld8p<F32>(dWhh, (size_t)r*HH + quad*8));
        Bd[g][3] = u2b8(ld8p<F32>(dWhh, (size_t)r*HH + 32 + quad*8));
    }
    bf16x8 Ba[2][4];
    #pragma unroll
    for (int kb = 0; kb < 4; ++kb)
        Ba[0][kb] = u2b8(ld8p<F32>(attnW, (size_t)(wv*16+col)*128 + kb*32 + quad*8));
    if (wv < 2){
        #pragma unroll
        for (int kb = 0; kb < 4; ++kb)
            Ba[1][kb] = u2b8(ld8p<F32>(attnW, (size_t)((4+wv)*16+col)*128 + kb*32 + quad*8));
    } else {
        #pragma unroll
        for (int kb = 0; kb < 4; ++kb) Ba[1][kb] = Ba[0][kb];
    }
    bf16x8 Bc[4];
    #pragma unroll
    for (int kb = 0; kb < 4; ++kb)
        Bc[kb] = u2b8(ld8p<F32>(combW, (size_t)(wv*16+col)*128 + kb*32 + quad*8));
    bf16x8 zz = {0,0,0,0,0,0,0,0};
    bf16x8 eBf = zz;
    if (quad == 0) eBf = u2b8(ld8p<F32>(embW, (size_t)(wv*16+col)*CC));
    bf16x8 oBf0 = zz, oBf1 = zz;
    if (col < CC){
        oBf0 = u2b8(ld8p<F32>(outW, (size_t)col*HH + quad*8));
        oBf1 = u2b8(ld8p<F32>(outW, (size_t)col*HH + 32 + quad*8));
    }

    float* decB  = (float*)(uni + 0);
    float* attnB = (float*)(uni + 1024);
    float* embB  = (float*)(uni + 1408);
    float* combB = (float*)(uni + 1664);
    float* outB  = (float*)(uni + 1920);
    float* Lg    = (float*)(uni + 1952);
    u16t*  awB   = (u16t*)(uni + 5024);
    u16t*  Ae    = (u16t*)(uni + 6560);
    u16t*  Ah0   = (u16t*)(uni + 8608);
    u16t*  Ah1   = (u16t*)(uni + 10656);
    u16t*  Actx  = (u16t*)(uni + 12704);
    u16t*  Acmb  = (u16t*)(uni + 14752);
    u16t*  Apred = (u16t*)(uni + 16800);

    #pragma unroll
    for (int rr = 0; rr < 2; ++rr){
        int b = (quad*4 + r0 + rr) & 7;
        Ah0[aaddr(jmy, b)]     = hb16[rr];
        Ah0[aaddr(jmy, b+8)]   = hb16[rr];
    }
    decB[tid] = ldf<F32>(dbih, tid) + ldf<F32>(dbhh, tid);
    if (tid < LL) attnB[tid] = ldf<F32>(attnb, tid);
    if (tid < HH) embB[tid]  = ldf<F32>(embb, tid);
    if (tid < HH) combB[tid] = ldf<F32>(combb, tid);
    if (tid < CC) outB[tid]  = ldf<F32>(outb, tid);
    for (int n = tid; n < 1024; n += 256) Apred[n] = 0;
    __syncthreads();

    const u16t* ebp = eoG + (size_t)(b0 + wv*2) * 6144;
    uint4 eF0[12], eF1[12];
    #pragma unroll
    for (int f = 0; f < 12; ++f) eF0[f] = *(const uint4*)(ebp + f*512 + quad*128 + col*8);
    #pragma unroll
    for (int f = 0; f < 12; ++f) eF1[f] = *(const uint4*)(ebp + 6144 + f*512 + quad*128 + col*8);

    const int lgS = tid & 31, bS = tid >> 5;
    const bf16x8* AeV   = (const bf16x8*)Ae;
    const bf16x8* ActxV = (const bf16x8*)Actx;
    const bf16x8* AcmbV = (const bf16x8*)Acmb;
    const bf16x8* ApV   = (const bf16x8*)Apred;

    for (int t = 0; t < TT; ++t){
        u16t* AhR = (t & 1) ? Ah1 : Ah0;
        u16t* AhW = (t & 1) ? Ah0 : Ah1;
        const bf16x8* AhV = (const bf16x8*)AhR;

        {
            bf16x8 ap = ApV[quad*16 + col];
            float eb = embB[wv*16 + col];
            f32x4 a; a[0]=eb; a[1]=eb; a[2]=eb; a[3]=eb;
            a = __builtin_amdgcn_mfma_f32_16x16x32_bf16(ap, eBf, a, 0,0,0);
            #pragma unroll
            for (int r = 0; r < 4; ++r)
                Ae[aaddr(wv*16+col, quad*4 + r)] = f2b(fmaxf(a[r], 0.f));
        }
        __syncthreads();

        {
            bf16x8 ae0 = AeV[(0*4+quad)*16 + col], ae1 = AeV[(1*4+quad)*16 + col];
            bf16x8 ah0 = AhV[(0*4+quad)*16 + col], ah1 = AhV[(1*4+quad)*16 + col];
            const int ns = (wv < 2) ? 2 : 1;
            for (int s = 0; s < ns; ++s){
                int lt = (s == 0) ? wv : 4+wv;
                float bz = attnB[lt*16 + col];
                f32x4 a; a[0]=bz; a[1]=bz; a[2]=bz; a[3]=bz;
                a = __builtin_amdgcn_mfma_f32_16x16x32_bf16(ae0, Ba[s][0], a, 0,0,0);
                a = __builtin_amdgcn_mfma_f32_16x16x32_bf16(ae1, Ba[s][1], a, 0,0,0);
                a = __builtin_amdgcn_mfma_f32_16x16x32_bf16(ah0, Ba[s][2], a, 0,0,0);
                a = __builtin_amdgcn_mfma_f32_16x16x32_bf16(ah1, Ba[s][3], a, 0,0,0);
                if (quad < 2)
                    *(float4*)&Lg[(lt*16+col)*8 + quad*4] = make_float4(a[0],a[1],a[2],a[3]);
            }
        }
        __syncthreads();

        {
            int l = lgS*3;
            float ev0 = Lg[l*8 + bS], ev1 = Lg[(l+1)*8 + bS], ev2 = Lg[(l+2)*8 + bS];
            float mx = fmaxf(ev0, fmaxf(ev1, ev2));
            #pragma unroll
            for (int m = 16; m >= 1; m >>= 1) mx = fmaxf(mx, __shfl_xor(mx, m, 32));
            float e0 = __expf(ev0 - mx), e1 = __expf(ev1 - mx), e2 = __expf(ev2 - mx);
            float sm = e0 + e1 + e2;
            #pragma unroll
            for (int m = 16; m >= 1; m >>= 1) sm += __shfl_xor(sm, m, 32);
            float inv = rcpf(sm);
            awB[bS*96 + l]     = f2b(e0*inv);
            awB[bS*96 + l + 1] = f2b(e1*inv);
            awB[bS*96 + l + 2] = f2b(e2*inv);
        }
        {
            const u16t* ap0 = awB + (wv*2)*96;
            bf16x8 f0 = *(const bf16x8*)(ap0 + quad*8);
            bf16x8 f1 = *(const bf16x8*)(ap0 + 32 + quad*8);
            bf16x8 f2 = *(const bf16x8*)(ap0 + 64 + quad*8);
            #pragma unroll
            for (int nt = 0; nt < 4; ++nt){
                f32x4 a; a[0]=0.f; a[1]=0.f; a[2]=0.f; a[3]=0.f;
                a = __builtin_amdgcn_mfma_f32_16x16x32_bf16(f0, u2b8(eF0[nt*3+0]), a, 0,0,0);
                a = __builtin_amdgcn_mfma_f32_16x16x32_bf16(f1, u2b8(eF0[nt*3+1]), a, 0,0,0);
                a = __builtin_amdgcn_mfma_f32_16x16x32_bf16(f2, u2b8(eF0[nt*3+2]), a, 0,0,0);
                if (quad == 0){
                    u16t v = f2b(a[0]);
                    Actx[aaddr(nt*16+col, wv*2)]   = v;
                    Actx[aaddr(nt*16+col, wv*2+8)] = v;
                }
            }
            const u16t* ap1 = awB + (wv*2+1)*96;
            bf16x8 g0 = *(const bf16x8*)(ap1 + quad*8);
            bf16x8 g1 = *(const bf16x8*)(ap1 + 32 + quad*8);
            bf16x8 g2 = *(const bf16x8*)(ap1 + 64 + quad*8);
            #pragma unroll
            for (int nt = 0; nt < 4; ++nt){
                f32x4 a; a[0]=0.f; a[1]=0.f; a[2]=0.f; a[3]=0.f;
                a = __builtin_amdgcn_mfma_f32_16x16x32_bf16(g0, u2b8(eF1[nt*3+0]), a, 0,0,0);
                a = __builtin_amdgcn_mfma_f32_16x16x32_bf16(g1, u2b8(eF1[nt*3+1]), a, 0,0,0);
                a = __builtin_amdgcn_mfma_f32_16x16x32_bf16(g2, u2b8(eF1[nt*3+2]), a, 0,0,0);
                if (quad == 0){
                    u16t v = f2b(a[0]);
                    Actx[aaddr(nt*16+col, wv*2+1)] = v;
                    Actx[aaddr(nt*16+col, wv*2+9)] = v;
                }
            }
        }
        __syncthreads();

        {
            bf16x8 ae0 = AeV[(0*4+quad)*16 + col],   ae1 = AeV[(1*4+quad)*16 + col];
            bf16x8 ax0 = ActxV[(0*4+quad)*16 + col], ax1 = ActxV[(1*4+quad)*16 + col];
            float bz = combB[wv*16 + col];
            f32x4 a; a[0]=bz; a[1]=bz; a[2]=bz; a[3]=bz;
            a = __builtin_amdgcn_mfma_f32_16x16x32_bf16(ae0, Bc[0], a, 0,0,0);
            a = __builtin_amdgcn_mfma_f32_16x16x32_bf16(ae1, Bc[1], a, 0,0,0);
            a = __builtin_amdgcn_mfma_f32_16x16x32_bf16(ax0, Bc[2], a, 0,0,0);
            a = __builtin_amdgcn_mfma_f32_16x16x32_bf16(ax1, Bc[3], a, 0,0,0);
            #pragma unroll
            for (int r = 0; r < 4; ++r)
                Acmb[aaddr(wv*16+col, quad*4 + r)] = f2b(a[r]);
        }
        __syncthreads();

        {
            bf16x8 ac0 = AcmbV[(0*4+quad)*16 + col], ac1 = AcmbV[(1*4+quad)*16 + col];
            bf16x8 ah0 = AhV[(0*4+quad)*16 + col],   ah1 = AhV[(1*4+quad)*16 + col];
            f32x4 g4[4];
            #pragma unroll
            for (int g = 0; g < 4; ++g){
                float bz = decB[g*64 + wv*16 + col];
                f32x4 a; a[0]=bz; a[1]=bz; a[2]=bz; a[3]=bz;
                a = __builtin_amdgcn_mfma_f32_16x16x32_bf16(ac0, Bd[g][0], a, 0,0,0);
                a = __builtin_amdgcn_mfma_f32_16x16x32_bf16(ac1, Bd[g][1], a, 0,0,0);
                a = __builtin_amdgcn_mfma_f32_16x16x32_bf16(ah0, Bd[g][2], a, 0,0,0);
                a = __builtin_amdgcn_mfma_f32_16x16x32_bf16(ah1, Bd[g][3], a, 0,0,0);
                g4[g] = a;
            }
            #pragma unroll
            for (int rr = 0; rr < 2; ++rr){
                int r = r0 + rr;
                int b = (quad*4 + r) & 7;
                float c = sigm(g4[1][r])*creg[rr] + sigm(g4[0][r])*tanh2(g4[2][r]);
                float h = sigm(g4[3][r])*tanh2(c);
                creg[rr] = c;
                u16t hv = f2b(h);
                AhW[aaddr(jmy, b)]   = hv;
                AhW[aaddr(jmy, b+8)] = hv;
            }
        }
        __syncthreads();

        if (wv == 0){
            const bf16x8* AhWV = (const bf16x8*)AhW;
            bf16x8 xh0 = AhWV[(0*4+quad)*16 + col];
            bf16x8 xh1 = AhWV[(1*4+quad)*16 + col];
            float ob = outB[col & 7];
            f32x4 a; a[0]=ob; a[1]=ob; a[2]=ob; a[3]=ob;
            a = __builtin_amdgcn_mfma_f32_16x16x32_bf16(xh0, oBf0, a, 0,0,0);
            a = __builtin_amdgcn_mfma_f32_16x16x32_bf16(xh1, oBf1, a, 0,0,0);
            if (col < CC){
                #pragma unroll
                for (int r = 0; r < 4; ++r){
                    int m = quad*4 + r, b = m & 7;
                    float p = a[r];
                    Apred[aaddr(col, m)] = f2b(p);
                    if (m < 8)
                        stf<F32>(outp, ((size_t)(b0+b)*TT + t)*CC + col, p + slp[col*10 + b]);
                }
            }
        }
        __syncthreads();
    }
}

// --------------------------------------------------------------- launch -----
extern "C" void kernel_launch(void* const* d_in, const int* in_sizes, int n_in,
                              void* d_out, int out_size, void* d_ws, size_t ws_size,
                              hipStream_t stream)
{
    (void)out_size;
    // Host-side dtype dispatch: ebih (d_in[6]) has 256 elements -> 512B (bf16)
    // or 1024B (f32). If in_sizes is ambiguous (element counts / missing),
    // launch both templates (device-side probe guards correctness).
    bool doBF = true, doF32 = true;
    if (in_sizes && n_in > 6){
        if (in_sizes[6] == 512)  doF32 = false;
        else if (in_sizes[6] == 1024) doBF = false;
    }
    // eoG: 4096*96*64*2B = 50,331,648 B.  cG (f32 c-state): 4096*64*4B = 1,048,576 B.
    u16t* eoG = (u16t*)d_ws;
    if (ws_size >= 50331648ull + 1048576ull){
        float* cG = (float*)((char*)d_ws + 50331648ull);
        if (doBF){
            // encoder: BT=16, 256 blocks (1 block/CU), M rows all real
            enc16_g<false><<<256, 256, 0, stream>>>(
                d_in[0], d_in[4], d_in[5], d_in[6], d_in[7], eoG, cG);
            dec8_g<false><<<NB, 256, 0, stream>>>(
                d_in[0],
                d_in[8],  d_in[9],  d_in[10], d_in[11],
                d_in[12], d_in[13], d_in[14], d_in[15],
                d_in[16], d_in[17], d_in[18], d_in[19],
                d_out, eoG, cG);
        }
        if (doF32){
            enc16_g<true ><<<256, 256, 0, stream>>>(
                d_in[0], d_in[4], d_in[5], d_in[6], d_in[7], eoG, cG);
            dec8_g<true ><<<NB, 256, 0, stream>>>(
                d_in[0],
                d_in[8],  d_in[9],  d_in[10], d_in[11],
                d_in[12], d_in[13], d_in[14], d_in[15],
                d_in[16], d_in[17], d_in[18], d_in[19],
                d_out, eoG, cG);
        }
    } else {
        // fallback: proven fused kernel (ws only fits eoG)
        if (doBF)
            fused_g<false><<<NB, 256, 0, stream>>>(
                d_in[0],
                d_in[4],  d_in[5],  d_in[6],  d_in[7],
                d_in[8],  d_in[9],  d_in[10], d_in[11],
                d_in[12], d_in[13], d_in[14], d_in[15],
                d_in[16], d_in[17], d_in[18], d_in[19],
                d_out, eoG);
        if (doF32)
            fused_g<true><<<NB, 256, 0, stream>>>(
                d_in[0],
                d_in[4],  d_in[5],  d_in[6],  d_in[7],
                d_in[8],  d_in[9],  d_in[10], d_in[11],
                d_in[12], d_in[13], d_in[14], d_in[15],
                d_in[16], d_in[17], d_in[18], d_in[19],
                d_out, eoG);
    }
}